// Round 9
// baseline (630.361 us; speedup 1.0000x reference)
//
#include <hip/hip_runtime.h>

#define NM 2048
#define EM 32768
#define NP 8192
#define EP 262144

typedef __attribute__((ext_vector_type(8))) short short8;
typedef __attribute__((ext_vector_type(4))) float f32x4;

#define LOG2E 1.44269504088896340736f

__device__ __forceinline__ float e2(float x) { return __builtin_amdgcn_exp2f(x); }
// pack two fp32 -> bf16x2 by TRUNCATION (1 inst); P in [0,1], validated r7/r8 (absmax 0.031)
__device__ __forceinline__ unsigned int pk_bf16_tr(float a, float b) {
    return __builtin_amdgcn_perm(__float_as_uint(a), __float_as_uint(b), 0x03020706u);
}
__device__ __forceinline__ unsigned short cvt_bf16(float f) {
    unsigned int u = __float_as_uint(f);
    u = (u + 0x7fff + ((u >> 16) & 1)) >> 16;   // RNE
    return (unsigned short)u;
}

// ---------------- phase 1: histogram of dst (both graphs) ----------------
__global__ __launch_bounds__(256) void hist_kernel(
    const int* __restrict__ ei_m, const int* __restrict__ ei_p,
    int* __restrict__ cnt_m, int* __restrict__ cnt_p)
{
    int idx = blockIdx.x * 256 + threadIdx.x;
    if (idx < EM) atomicAdd(&cnt_m[ei_m[EM + idx]], 1);
    int j = idx - EM;
    if (j >= 0 && j < EP) atomicAdd(&cnt_p[ei_p[EP + j]], 1);
}

// ---------------- phase 2: exclusive prefix sum (block 0 = mol, block 1 = prot) ----------------
__global__ __launch_bounds__(256) void scan_kernel(
    const int* __restrict__ cnt_m, const int* __restrict__ cnt_p,
    int* __restrict__ start_m, int* __restrict__ start_p,
    int* __restrict__ cur_m, int* __restrict__ cur_p)
{
    const int* cnt; int* start; int* cur; int n;
    if (blockIdx.x == 0) { cnt = cnt_m; start = start_m; cur = cur_m; n = NM; }
    else                 { cnt = cnt_p; start = start_p; cur = cur_p; n = NP; }
    int per = n >> 8;
    int tid = threadIdx.x;
    int base = tid * per;
    int s = 0;
    for (int i = 0; i < per; i++) s += cnt[base + i];
    __shared__ int wsum[4];
    int lane = tid & 63, w = tid >> 6;
    int v = s;
    #pragma unroll
    for (int off = 1; off < 64; off <<= 1) {
        int u = __shfl_up(v, off, 64);
        if (lane >= off) v += u;
    }
    if (lane == 63) wsum[w] = v;
    __syncthreads();
    int wo = 0;
    for (int i = 0; i < w; i++) wo += wsum[i];
    int run = wo + v - s;   // exclusive prefix for this thread's range
    for (int i = 0; i < per; i++) {
        start[base + i] = run; cur[base + i] = run;
        run += cnt[base + i];
    }
    if (tid == 255) start[n] = run;
}

// ------- phase 3: scatter packed (edge<<sh)|src into dst-sorted order -------
__global__ __launch_bounds__(256) void scatter_kernel(
    const int* __restrict__ ei_m, const int* __restrict__ ei_p,
    int* __restrict__ cur_m, int* __restrict__ cur_p,
    int* __restrict__ pidx_m, int* __restrict__ pidx_p)
{
    int idx = blockIdx.x * 256 + threadIdx.x;
    if (idx < EM) {
        int d = ei_m[EM + idx];
        int pos = atomicAdd(&cur_m[d], 1);
        pidx_m[pos] = (idx << 11) | ei_m[idx];          // NM=2048 -> 11 src bits
    }
    int j = idx - EM;
    if (j >= 0 && j < EP) {
        int d = ei_p[EP + j];
        int pos = atomicAdd(&cur_p[d], 1);
        pidx_p[pos] = (j << 13) | ei_p[j];              // NP=8192 -> 13 src bits
    }
}

// ------- phase 4: atomic-free segmented reduce; h0 = x + mean(relu(x[src]+ea)) -------
__global__ __launch_bounds__(256) void node_aggr_kernel(
    const float* __restrict__ x_m, const float* __restrict__ ea_m,
    const int* __restrict__ start_m, const int* __restrict__ pidx_m,
    const float* __restrict__ x_p, const float* __restrict__ ea_p,
    const int* __restrict__ start_p, const int* __restrict__ pidx_p,
    float* __restrict__ h0_m, float* __restrict__ h0_p)
{
    int wave = threadIdx.x >> 6, lane = threadIdx.x & 63;
    int nid = blockIdx.x * 4 + wave;
    const float *x, *ea; const int *start, *pidx; float* h0; int n, sh, msk;
    if (nid < NM) { x = x_m; ea = ea_m; start = start_m; pidx = pidx_m; h0 = h0_m; n = nid; sh = 11; msk = 2047; }
    else          { x = x_p; ea = ea_p; start = start_p; pidx = pidx_p; h0 = h0_p; n = nid - NM; sh = 13; msk = 8191; }
    int b  = __builtin_amdgcn_readfirstlane(start[n]);
    int e  = __builtin_amdgcn_readfirstlane(start[n + 1]);
    int deg = e - b;
    const int* pp = pidx + b;
    float acc = 0.f;
    int j = 0;
    for (; j + 8 <= deg; j += 8) {
        int v0 = __builtin_amdgcn_readfirstlane(pp[j]);
        int v1 = __builtin_amdgcn_readfirstlane(pp[j + 1]);
        int v2 = __builtin_amdgcn_readfirstlane(pp[j + 2]);
        int v3 = __builtin_amdgcn_readfirstlane(pp[j + 3]);
        int v4 = __builtin_amdgcn_readfirstlane(pp[j + 4]);
        int v5 = __builtin_amdgcn_readfirstlane(pp[j + 5]);
        int v6 = __builtin_amdgcn_readfirstlane(pp[j + 6]);
        int v7 = __builtin_amdgcn_readfirstlane(pp[j + 7]);
        float a0 = ea[(size_t)(((unsigned)v0) >> sh) * 64 + lane];
        float a1 = ea[(size_t)(((unsigned)v1) >> sh) * 64 + lane];
        float a2 = ea[(size_t)(((unsigned)v2) >> sh) * 64 + lane];
        float a3 = ea[(size_t)(((unsigned)v3) >> sh) * 64 + lane];
        float a4 = ea[(size_t)(((unsigned)v4) >> sh) * 64 + lane];
        float a5 = ea[(size_t)(((unsigned)v5) >> sh) * 64 + lane];
        float a6 = ea[(size_t)(((unsigned)v6) >> sh) * 64 + lane];
        float a7 = ea[(size_t)(((unsigned)v7) >> sh) * 64 + lane];
        float y0 = x[(size_t)(v0 & msk) * 64 + lane];
        float y1 = x[(size_t)(v1 & msk) * 64 + lane];
        float y2 = x[(size_t)(v2 & msk) * 64 + lane];
        float y3 = x[(size_t)(v3 & msk) * 64 + lane];
        float y4 = x[(size_t)(v4 & msk) * 64 + lane];
        float y5 = x[(size_t)(v5 & msk) * 64 + lane];
        float y6 = x[(size_t)(v6 & msk) * 64 + lane];
        float y7 = x[(size_t)(v7 & msk) * 64 + lane];
        acc += fmaxf(y0 + a0, 0.f); acc += fmaxf(y1 + a1, 0.f);
        acc += fmaxf(y2 + a2, 0.f); acc += fmaxf(y3 + a3, 0.f);
        acc += fmaxf(y4 + a4, 0.f); acc += fmaxf(y5 + a5, 0.f);
        acc += fmaxf(y6 + a6, 0.f); acc += fmaxf(y7 + a7, 0.f);
    }
    for (; j < deg; ++j) {
        int v0 = __builtin_amdgcn_readfirstlane(pp[j]);
        acc += fmaxf(x[(size_t)(v0 & msk) * 64 + lane] + ea[(size_t)(((unsigned)v0) >> sh) * 64 + lane], 0.f);
    }
    float aggr = acc / fmaxf((float)deg, 1.f);
    h0[(size_t)n * 64 + lane] = x[(size_t)n * 64 + lane] + aggr;
}

// ------- fused GINE MLP + QKV (both graphs): one staging of rows, phased LDS weights -------
// phase A: sh1 = relu(h0@W1+b1); phase B: h = relu(sh1@W2+b2) -> global + sh0;
// phase C: Q,K (+norms); phase D: V.  57 KB LDS -> 2 blocks/CU.
__global__ __launch_bounds__(256) void mlp_qkv_kernel(
    const float* __restrict__ h0_m, const float* __restrict__ h0_p,
    const float* __restrict__ w1m, const float* __restrict__ b1m,
    const float* __restrict__ w2m, const float* __restrict__ b2m,
    const float* __restrict__ w1p, const float* __restrict__ b1p,
    const float* __restrict__ w2p, const float* __restrict__ b2p,
    const float* __restrict__ wq_m, const float* __restrict__ bq_m,
    const float* __restrict__ wk_m, const float* __restrict__ bk_m,
    const float* __restrict__ wv_m, const float* __restrict__ bv_m,
    const float* __restrict__ wq_p, const float* __restrict__ bq_p,
    const float* __restrict__ wk_p, const float* __restrict__ bk_p,
    const float* __restrict__ wv_p, const float* __restrict__ bv_p,
    float* __restrict__ hm, float* __restrict__ hp,
    unsigned short* __restrict__ Qm, unsigned short* __restrict__ Km, unsigned short* __restrict__ Vtm,
    unsigned short* __restrict__ Qp, unsigned short* __restrict__ Kp, unsigned short* __restrict__ Vtp,
    int* __restrict__ norms)
{
    const float *h0, *w1, *b1, *w2, *b2, *wq, *bq, *wk, *bk, *wv, *bv;
    float* hout; unsigned short *Q, *K, *Vt; int row0, N, nbase;
    if (blockIdx.x < NM / 16) {
        h0 = h0_m; w1 = w1m; b1 = b1m; w2 = w2m; b2 = b2m;
        wq = wq_m; bq = bq_m; wk = wk_m; bk = bk_m; wv = wv_m; bv = bv_m;
        hout = hm; Q = Qm; K = Km; Vt = Vtm; N = NM; row0 = blockIdx.x * 16; nbase = 0;
    } else {
        h0 = h0_p; w1 = w1p; b1 = b1p; w2 = w2p; b2 = b2p;
        wq = wq_p; bq = bq_p; wk = wk_p; bk = bk_p; wv = wv_p; bv = bv_p;
        hout = hp; Q = Qp; K = Kp; Vt = Vtp; N = NP; row0 = (blockIdx.x - NM / 16) * 16; nbase = 2;
    }
    __shared__ float sWa[4096], sWb[4096], sWc[4096];
    __shared__ float sb1[64], sb2[64], sbq[64], sbk[64], sbv[64];
    __shared__ float sh0[16][64], sh1[16][64];
    __shared__ float rmx[8];
    int t = threadIdx.x;
    // stage: sWa=W1, sWb=W2, sWc=Wq
    for (int i = t; i < 4096; i += 256) { sWa[i] = w1[i]; sWb[i] = w2[i]; sWc[i] = wq[i]; }
    if (t < 64) { sb1[t] = b1[t]; sb2[t] = b2[t]; sbq[t] = bq[t]; sbk[t] = bk[t]; sbv[t] = bv[t]; }
    for (int i = t; i < 16 * 64; i += 256) {
        int r = i >> 6, c = i & 63;
        sh0[r][c] = h0[(size_t)(row0 + r) * 64 + c];
    }
    __syncthreads();
    int j = t & 63, rs = t >> 6;
    // phase A: sh1 = relu(sh0 @ W1 + b1)
    for (int r = rs; r < 16; r += 4) {
        float a = sb1[j];
        #pragma unroll
        for (int c = 0; c < 64; c++) a += sh0[r][c] * sWa[c * 64 + j];
        sh1[r][j] = fmaxf(a, 0.0f);
    }
    __syncthreads();   // sh1 ready; sWa free
    // phase B: h = relu(sh1 @ W2 + b2) -> global + sh0; reload sWa = Wk
    for (int r = rs; r < 16; r += 4) {
        float a = sb2[j];
        #pragma unroll
        for (int c = 0; c < 64; c++) a += sh1[r][c] * sWb[c * 64 + j];
        float hval = fmaxf(a, 0.0f);
        hout[(size_t)(row0 + r) * 64 + j] = hval;
        sh0[r][j] = hval;
    }
    for (int i = t; i < 4096; i += 256) sWa[i] = wk[i];
    __syncthreads();   // sh0=h, sWa=Wk ready; sWb free
    // phase C: Q (sWc), K (sWa) + norms; reload sWb = Wv
    float qmx = 0.f, kmx = 0.f;
    for (int r = rs; r < 16; r += 4) {
        float aq = sbq[j], ak = sbk[j];
        #pragma unroll
        for (int c = 0; c < 64; c++) {
            float h = sh0[r][c];
            aq += h * sWc[c * 64 + j];
            ak += h * sWa[c * 64 + j];
        }
        float qs = aq * (0.25f * LOG2E);      // fold 1/sqrt(HD) and log2(e)
        size_t o = (size_t)(row0 + r) * 64 + j;
        Q[o] = cvt_bf16(qs);
        K[o] = cvt_bf16(ak);
        float qsq = qs * qs, ksq = ak * ak;
        #pragma unroll
        for (int o2 = 1; o2 <= 8; o2 <<= 1) {
            qsq += __shfl_xor(qsq, o2, 64);
            ksq += __shfl_xor(ksq, o2, 64);
        }
        qmx = fmaxf(qmx, qsq);
        kmx = fmaxf(kmx, ksq);
    }
    for (int i = t; i < 4096; i += 256) sWb[i] = wv[i];
    qmx = fmaxf(qmx, __shfl_xor(qmx, 16, 64)); qmx = fmaxf(qmx, __shfl_xor(qmx, 32, 64));
    kmx = fmaxf(kmx, __shfl_xor(kmx, 16, 64)); kmx = fmaxf(kmx, __shfl_xor(kmx, 32, 64));
    if (j == 0) { rmx[rs] = qmx; rmx[4 + rs] = kmx; }
    __syncthreads();   // sWb=Wv ready
    // phase D: V (transposed store)
    for (int r = rs; r < 16; r += 4) {
        float av = sbv[j];
        #pragma unroll
        for (int c = 0; c < 64; c++) av += sh0[r][c] * sWb[c * 64 + j];
        Vt[(size_t)j * N + row0 + r] = cvt_bf16(av);
    }
    if (t == 0) {
        float q4 = fmaxf(fmaxf(rmx[0], rmx[1]), fmaxf(rmx[2], rmx[3]));
        float k4 = fmaxf(fmaxf(rmx[4], rmx[5]), fmaxf(rmx[6], rmx[7]));
        atomicMax(&norms[nbase],     __float_as_int(sqrtf(q4)));
        atomicMax(&norms[nbase + 1], __float_as_int(sqrtf(k4)));
    }
}

// ------- MFMA flash-attention: fixed C-S bound m, 32 queries/wave, PIPELINED P -------
// PV MFMA deferred one iteration: P double-buffered in LDS, ds_read issued a full
// exp/pack phase ahead of its consuming MFMA -> no per-iter LDS RAW stall.
__global__ __launch_bounds__(256) void attn_kernel(
    const unsigned short* __restrict__ Qm, const unsigned short* __restrict__ Km,
    const unsigned short* __restrict__ Vtm,
    const unsigned short* __restrict__ Qp, const unsigned short* __restrict__ Kp,
    const unsigned short* __restrict__ Vtp,
    const int* __restrict__ norms, float* __restrict__ partial)
{
    __shared__ unsigned int plds[4][2][2][16][20];   // [wave][qtile][buf][qrow][16+pad]
    int t = threadIdx.x;
    int wave = t >> 6;
    int lane = t & 63;
    int qrow = lane & 15;
    int quad = lane >> 4;
    int W = blockIdx.x * 4 + wave;

    const unsigned short *Q, *K, *Vt; int Nk; float m;
    int chunk, h, qt2, Tbase, T1off;
    if (W < 2048) {
        Q = Qm; K = Kp; Vt = Vtp; Nk = NP;
        m = __int_as_float(norms[0]) * __int_as_float(norms[3]);
        chunk = W & 7; h = (W >> 3) & 3; qt2 = W >> 5;
        Tbase = W + qt2 * 32; T1off = 32;
    } else {
        int W2 = W - 2048;
        Q = Qp; K = Km; Vt = Vtm; Nk = NM;
        m = __int_as_float(norms[2]) * __int_as_float(norms[1]);
        chunk = W2 & 1; h = (W2 >> 1) & 3; qt2 = W2 >> 3;
        Tbase = 4096 + W2 + qt2 * 8; T1off = 8;
    }

    short8 qfA = {}, qfB = {};
    if (quad < 2) {
        qfA = *(const short8*)(Q + ((size_t)(qt2 * 32 + qrow)) * 64 + h * 16 + quad * 8);
        qfB = *(const short8*)(Q + ((size_t)(qt2 * 32 + 16 + qrow)) * 64 + h * 16 + quad * 8);
    }

    const f32x4 zero4 = {0.f, 0.f, 0.f, 0.f};
    int kbase = chunk * 1024;
    const unsigned short* krow = K + (size_t)(kbase + qrow) * 64 + h * 16 + quad * 8;
    const unsigned short* vrow = Vt + ((size_t)(h * 16 + qrow)) * Nk + kbase + quad * 8;

    float lA = 0.0f, lB = 0.0f;
    f32x4 accA = zero4, accB = zero4;

    short8 kf0p[2], kf1p[2], vfp[2];
    #pragma unroll
    for (int i = 0; i < 2; ++i) {
        kf0p[i] = (short8){}; kf1p[i] = (short8){};
        if (quad < 2) {
            kf0p[i] = *(const short8*)(krow + (size_t)(i * 32) * 64);
            kf1p[i] = *(const short8*)(krow + (size_t)(i * 32 + 16) * 64);
        }
        vfp[i] = *(const short8*)(vrow + i * 32);
    }

    short8 vf_prev;
    // ---- it = 0 (peeled: QK + store P, no PV yet) ----
    {
        short8 kf0 = kf0p[0], kf1 = kf1p[0];
        vf_prev = vfp[0];
        {   // prefetch it=2 into slot 0
            if (quad < 2) {
                kf0p[0] = *(const short8*)(krow + (size_t)(2 * 32) * 64);
                kf1p[0] = *(const short8*)(krow + (size_t)(2 * 32 + 16) * 64);
            }
            vfp[0] = *(const short8*)(vrow + 2 * 32);
        }
        f32x4 s0A = __builtin_amdgcn_mfma_f32_16x16x32_bf16(kf0, qfA, zero4, 0, 0, 0);
        f32x4 s1A = __builtin_amdgcn_mfma_f32_16x16x32_bf16(kf1, qfA, zero4, 0, 0, 0);
        f32x4 s0B = __builtin_amdgcn_mfma_f32_16x16x32_bf16(kf0, qfB, zero4, 0, 0, 0);
        f32x4 s1B = __builtin_amdgcn_mfma_f32_16x16x32_bf16(kf1, qfB, zero4, 0, 0, 0);
        float a00 = e2(s0A.x - m), a01 = e2(s0A.y - m), a02 = e2(s0A.z - m), a03 = e2(s0A.w - m);
        float a10 = e2(s1A.x - m), a11 = e2(s1A.y - m), a12 = e2(s1A.z - m), a13 = e2(s1A.w - m);
        float b00 = e2(s0B.x - m), b01 = e2(s0B.y - m), b02 = e2(s0B.z - m), b03 = e2(s0B.w - m);
        float b10 = e2(s1B.x - m), b11 = e2(s1B.y - m), b12 = e2(s1B.z - m), b13 = e2(s1B.w - m);
        lA += (((a00 + a01) + (a02 + a03)) + ((a10 + a11) + (a12 + a13)));
        lB += (((b00 + b01) + (b02 + b03)) + ((b10 + b11) + (b12 + b13)));
        uint2 wA0; wA0.x = pk_bf16_tr(a00, a01); wA0.y = pk_bf16_tr(a02, a03);
        uint2 wA1; wA1.x = pk_bf16_tr(a10, a11); wA1.y = pk_bf16_tr(a12, a13);
        uint2 wB0; wB0.x = pk_bf16_tr(b00, b01); wB0.y = pk_bf16_tr(b02, b03);
        uint2 wB1; wB1.x = pk_bf16_tr(b10, b11); wB1.y = pk_bf16_tr(b12, b13);
        *(uint2*)&plds[wave][0][0][qrow][quad * 2] = wA0;
        *(uint2*)&plds[wave][0][0][qrow][8 + quad * 2] = wA1;
        *(uint2*)&plds[wave][1][0][qrow][quad * 2] = wB0;
        *(uint2*)&plds[wave][1][0][qrow][8 + quad * 2] = wB1;
    }

    for (int it = 1; it < 32; ++it) {
        short8 kf0 = kf0p[it & 1], kf1 = kf1p[it & 1], vf = vfp[it & 1];
        // early-issue read of previous iteration's P (other buffer -> no WAR)
        short8 pfA = *(short8*)&plds[wave][0][(it - 1) & 1][qrow][quad * 4];
        short8 pfB = *(short8*)&plds[wave][1][(it - 1) & 1][qrow][quad * 4];
        if (it < 30) {
            int off = (it + 2) * 32;
            if (quad < 2) {
                kf0p[it & 1] = *(const short8*)(krow + (size_t)off * 64);
                kf1p[it & 1] = *(const short8*)(krow + (size_t)(off + 16) * 64);
            }
            vfp[it & 1] = *(const short8*)(vrow + off);
        }

        f32x4 s0A = __builtin_amdgcn_mfma_f32_16x16x32_bf16(kf0, qfA, zero4, 0, 0, 0);
        f32x4 s1A = __builtin_amdgcn_mfma_f32_16x16x32_bf16(kf1, qfA, zero4, 0, 0, 0);
        f32x4 s0B = __builtin_amdgcn_mfma_f32_16x16x32_bf16(kf0, qfB, zero4, 0, 0, 0);
        f32x4 s1B = __builtin_amdgcn_mfma_f32_16x16x32_bf16(kf1, qfB, zero4, 0, 0, 0);

        float a00 = e2(s0A.x - m), a01 = e2(s0A.y - m), a02 = e2(s0A.z - m), a03 = e2(s0A.w - m);
        float a10 = e2(s1A.x - m), a11 = e2(s1A.y - m), a12 = e2(s1A.z - m), a13 = e2(s1A.w - m);
        float b00 = e2(s0B.x - m), b01 = e2(s0B.y - m), b02 = e2(s0B.z - m), b03 = e2(s0B.w - m);
        float b10 = e2(s1B.x - m), b11 = e2(s1B.y - m), b12 = e2(s1B.z - m), b13 = e2(s1B.w - m);
        lA += (((a00 + a01) + (a02 + a03)) + ((a10 + a11) + (a12 + a13)));
        lB += (((b00 + b01) + (b02 + b03)) + ((b10 + b11) + (b12 + b13)));

        uint2 wA0; wA0.x = pk_bf16_tr(a00, a01); wA0.y = pk_bf16_tr(a02, a03);
        uint2 wA1; wA1.x = pk_bf16_tr(a10, a11); wA1.y = pk_bf16_tr(a12, a13);
        uint2 wB0; wB0.x = pk_bf16_tr(b00, b01); wB0.y = pk_bf16_tr(b02, b03);
        uint2 wB1; wB1.x = pk_bf16_tr(b10, b11); wB1.y = pk_bf16_tr(b12, b13);
        *(uint2*)&plds[wave][0][it & 1][qrow][quad * 2] = wA0;
        *(uint2*)&plds[wave][0][it & 1][qrow][8 + quad * 2] = wA1;
        *(uint2*)&plds[wave][1][it & 1][qrow][quad * 2] = wB0;
        *(uint2*)&plds[wave][1][it & 1][qrow][8 + quad * 2] = wB1;

        accA = __builtin_amdgcn_mfma_f32_16x16x32_bf16(vf_prev, pfA, accA, 0, 0, 0);
        accB = __builtin_amdgcn_mfma_f32_16x16x32_bf16(vf_prev, pfB, accB, 0, 0, 0);
        vf_prev = vf;
    }
    // ---- epilogue: PV for it=31's P (buffer 1) ----
    {
        short8 pfA = *(short8*)&plds[wave][0][1][qrow][quad * 4];
        short8 pfB = *(short8*)&plds[wave][1][1][qrow][quad * 4];
        accA = __builtin_amdgcn_mfma_f32_16x16x32_bf16(vf_prev, pfA, accA, 0, 0, 0);
        accB = __builtin_amdgcn_mfma_f32_16x16x32_bf16(vf_prev, pfB, accB, 0, 0, 0);
    }

    float ltA = lA + __shfl_xor(lA, 16, 64); ltA += __shfl_xor(ltA, 32, 64);
    float ltB = lB + __shfl_xor(lB, 16, 64); ltB += __shfl_xor(ltB, 32, 64);

    float* pb0 = partial + (size_t)Tbase * 288;
    *(f32x4*)&pb0[qrow * 16 + quad * 4] = accA;
    if (quad == 0) pb0[272 + qrow] = ltA;
    float* pb1 = partial + (size_t)(Tbase + T1off) * 288;
    *(f32x4*)&pb1[qrow * 16 + quad * 4] = accB;
    if (quad == 0) pb1[272 + qrow] = ltB;
}

// ------- merge chunk partials + residual + layernorm (uniform m: plain sums) -------
__global__ __launch_bounds__(256) void merge_ln_kernel(
    const float* __restrict__ partial,
    const float* __restrict__ h_m, const float* __restrict__ h_p,
    const float* __restrict__ gm, const float* __restrict__ bm,
    const float* __restrict__ gp, const float* __restrict__ bp_,
    float* __restrict__ out)
{
    int t = threadIdx.x;
    int grow = blockIdx.x * 4 + (t >> 6);
    int c = t & 63;
    const float *pbase, *hbuf, *g, *bb; float* o; int NC, row;
    if (grow < NM) { pbase = partial;               hbuf = h_m; g = gm; bb = bm;  o = out;             NC = 8; row = grow; }
    else           { pbase = partial + 4096 * 288;  hbuf = h_p; g = gp; bb = bp_; o = out + NM * 64;   NC = 2; row = grow - NM; }
    int hi = c >> 4, d = c & 15;
    int qt = row >> 4, ql = row & 15;
    const float* base = pbase + (size_t)(qt * 4 + hi) * NC * 288;
    float L = 0.0f, A = 0.0f;
    for (int cc = 0; cc < NC; ++cc) {
        L += base[cc * 288 + 272 + ql];
        A += base[cc * 288 + ql * 16 + d];
    }
    float v = hbuf[(size_t)row * 64 + c] + A / L;
    float s = v;
    #pragma unroll
    for (int o2 = 32; o2 >= 1; o2 >>= 1) s += __shfl_xor(s, o2, 64);
    float mu = s * (1.0f / 64.0f);
    float dv = v - mu;
    float sq = dv * dv;
    #pragma unroll
    for (int o2 = 32; o2 >= 1; o2 >>= 1) sq += __shfl_xor(sq, o2, 64);
    float var = sq * (1.0f / 64.0f);
    o[(size_t)row * 64 + c] = dv * rsqrtf(var + 1e-5f) * g[c] + bb[c];
}

extern "C" void kernel_launch(void* const* d_in, const int* in_sizes, int n_in,
                              void* d_out, int out_size, void* d_ws, size_t ws_size,
                              hipStream_t stream)
{
    const float* x_mol   = (const float*)d_in[0];
    const int*   ei_mol  = (const int*)  d_in[1];
    const float* ea_mol  = (const float*)d_in[2];
    const float* x_prot  = (const float*)d_in[3];
    const int*   ei_prot = (const int*)  d_in[4];
    const float* ea_prot = (const float*)d_in[5];
    const float* mol_w1  = (const float*)d_in[6];
    const float* mol_b1  = (const float*)d_in[7];
    const float* mol_w2  = (const float*)d_in[8];
    const float* mol_b2  = (const float*)d_in[9];
    const float* prot_w1 = (const float*)d_in[10];
    const float* prot_b1 = (const float*)d_in[11];
    const float* prot_w2 = (const float*)d_in[12];
    const float* prot_b2 = (const float*)d_in[13];
    const float* mp_wq = (const float*)d_in[14]; const float* mp_bq = (const float*)d_in[15];
    const float* mp_wk = (const float*)d_in[16]; const float* mp_bk = (const float*)d_in[17];
    const float* mp_wv = (const float*)d_in[18]; const float* mp_bv = (const float*)d_in[19];
    const float* pm_wq = (const float*)d_in[20]; const float* pm_bq = (const float*)d_in[21];
    const float* pm_wk = (const float*)d_in[22]; const float* pm_bk = (const float*)d_in[23];
    const float* pm_wv = (const float*)d_in[24]; const float* pm_bv = (const float*)d_in[25];
    const float* ln_mol_g  = (const float*)d_in[26];
    const float* ln_mol_b  = (const float*)d_in[27];
    const float* ln_prot_g = (const float*)d_in[28];
    const float* ln_prot_b = (const float*)d_in[29];

    float* ws = (float*)d_ws;
    // float region
    float* h_mol   = ws;                         // 131072
    float* h_prot  = h_mol + 131072;             // 524288
    float* partial = h_prot + 524288;            // 8192*288 (mol tasks 0..4095, prot 4096..8191)
    float* h0_mol  = partial;                    // alias: dead before attn writes
    float* h0_prot = h0_mol + 131072;
    // int region
    int* ip      = (int*)(partial + 2359296);
    int* cnt_m   = ip;                 // 2048
    int* cnt_p   = cnt_m + 2048;       // 8192
    int* norms   = cnt_p + 8192;       // 4  (0=Qm,1=Km,2=Qp,3=Kp; float bits)
    int* start_m = norms + 4;          // 2052 (2049 used)
    int* start_p = start_m + 2052;     // 8196 (8193 used)
    int* cur_m   = start_p + 8196;     // 2048
    int* cur_p   = cur_m + 2048;       // 8192
    int* pidx_m  = cur_p + 8192;       // 32768
    int* pidx_p  = pidx_m + 32768;     // 262144
    // bf16 region; K arrays not region-last (prefetch may read 32 rows past chunk end)
    unsigned short* bf = (unsigned short*)(pidx_p + 262144);
    unsigned short* Qm  = bf;            // 131072
    unsigned short* Km  = Qm + 131072;   // 131072  (followed by Vtm: OOB-safe)
    unsigned short* Vtm = Km + 131072;   // 131072  [64][NM]
    unsigned short* Qp  = Vtm + 131072;  // 524288
    unsigned short* Kp  = Qp + 524288;   // 524288  (followed by Vtp: OOB-safe)
    unsigned short* Vtp = Kp + 524288;   // 524288  [64][NP]

    hipMemsetAsync(cnt_m, 0, (size_t)(2048 + 8192 + 4) * sizeof(int), stream);

    const int EB = (EM + EP) / 256;   // 1152
    hist_kernel<<<EB, 256, 0, stream>>>(ei_mol, ei_prot, cnt_m, cnt_p);
    scan_kernel<<<2, 256, 0, stream>>>(cnt_m, cnt_p, start_m, start_p, cur_m, cur_p);
    scatter_kernel<<<EB, 256, 0, stream>>>(ei_mol, ei_prot, cur_m, cur_p, pidx_m, pidx_p);
    node_aggr_kernel<<<(NM + NP) / 4, 256, 0, stream>>>(
        x_mol, ea_mol, start_m, pidx_m,
        x_prot, ea_prot, start_p, pidx_p, h0_mol, h0_prot);

    mlp_qkv_kernel<<<(NM + NP) / 16, 256, 0, stream>>>(
        h0_mol, h0_prot,
        mol_w1, mol_b1, mol_w2, mol_b2, prot_w1, prot_b1, prot_w2, prot_b2,
        mp_wq, mp_bq, pm_wk, pm_bk, pm_wv, pm_bv,
        pm_wq, pm_bq, mp_wk, mp_bk, mp_wv, mp_bv,
        h_mol, h_prot, Qm, Km, Vtm, Qp, Kp, Vtp, norms);

    // both directions, 32 queries/wave: 1024 blocks x 4 waves = 4096 tasks
    attn_kernel<<<1024, 256, 0, stream>>>(Qm, Km, Vtm, Qp, Kp, Vtp, norms, partial);

    float* out = (float*)d_out;
    merge_ln_kernel<<<(NM + NP) / 4, 256, 0, stream>>>(
        partial, h_mol, h_prot, ln_mol_g, ln_mol_b, ln_prot_g, ln_prot_b, out);
}

// Round 10
// 303.455 us; speedup vs baseline: 2.0773x; 2.0773x over previous
//
#include <hip/hip_runtime.h>

#define NM 2048
#define EM 32768
#define NP 8192
#define EP 262144

typedef __attribute__((ext_vector_type(8))) short short8;
typedef __attribute__((ext_vector_type(4))) float f32x4;

#define LOG2E 1.44269504088896340736f

__device__ __forceinline__ float e2(float x) { return __builtin_amdgcn_exp2f(x); }
// pack two fp32 -> bf16x2 by TRUNCATION (1 inst); P in [0,1], validated r7/r8 (absmax 0.031)
__device__ __forceinline__ unsigned int pk_bf16_tr(float a, float b) {
    return __builtin_amdgcn_perm(__float_as_uint(a), __float_as_uint(b), 0x03020706u);
}
__device__ __forceinline__ unsigned short cvt_bf16(float f) {
    unsigned int u = __float_as_uint(f);
    u = (u + 0x7fff + ((u >> 16) & 1)) >> 16;   // RNE
    return (unsigned short)u;
}

// ---------------- phase 1: histogram of dst (both graphs) ----------------
__global__ __launch_bounds__(256) void hist_kernel(
    const int* __restrict__ ei_m, const int* __restrict__ ei_p,
    int* __restrict__ cnt_m, int* __restrict__ cnt_p)
{
    int idx = blockIdx.x * 256 + threadIdx.x;
    if (idx < EM) atomicAdd(&cnt_m[ei_m[EM + idx]], 1);
    int j = idx - EM;
    if (j >= 0 && j < EP) atomicAdd(&cnt_p[ei_p[EP + j]], 1);
}

// ---------------- phase 2: exclusive prefix sum (block 0 = mol, block 1 = prot) ----------------
__global__ __launch_bounds__(256) void scan_kernel(
    const int* __restrict__ cnt_m, const int* __restrict__ cnt_p,
    int* __restrict__ start_m, int* __restrict__ start_p,
    int* __restrict__ cur_m, int* __restrict__ cur_p)
{
    const int* cnt; int* start; int* cur; int n;
    if (blockIdx.x == 0) { cnt = cnt_m; start = start_m; cur = cur_m; n = NM; }
    else                 { cnt = cnt_p; start = start_p; cur = cur_p; n = NP; }
    int per = n >> 8;
    int tid = threadIdx.x;
    int base = tid * per;
    int s = 0;
    for (int i = 0; i < per; i++) s += cnt[base + i];
    __shared__ int wsum[4];
    int lane = tid & 63, w = tid >> 6;
    int v = s;
    #pragma unroll
    for (int off = 1; off < 64; off <<= 1) {
        int u = __shfl_up(v, off, 64);
        if (lane >= off) v += u;
    }
    if (lane == 63) wsum[w] = v;
    __syncthreads();
    int wo = 0;
    for (int i = 0; i < w; i++) wo += wsum[i];
    int run = wo + v - s;   // exclusive prefix for this thread's range
    for (int i = 0; i < per; i++) {
        start[base + i] = run; cur[base + i] = run;
        run += cnt[base + i];
    }
    if (tid == 255) start[n] = run;
}

// ------- phase 3: scatter packed (edge<<sh)|src into dst-sorted order -------
__global__ __launch_bounds__(256) void scatter_kernel(
    const int* __restrict__ ei_m, const int* __restrict__ ei_p,
    int* __restrict__ cur_m, int* __restrict__ cur_p,
    int* __restrict__ pidx_m, int* __restrict__ pidx_p)
{
    int idx = blockIdx.x * 256 + threadIdx.x;
    if (idx < EM) {
        int d = ei_m[EM + idx];
        int pos = atomicAdd(&cur_m[d], 1);
        pidx_m[pos] = (idx << 11) | ei_m[idx];          // NM=2048 -> 11 src bits
    }
    int j = idx - EM;
    if (j >= 0 && j < EP) {
        int d = ei_p[EP + j];
        int pos = atomicAdd(&cur_p[d], 1);
        pidx_p[pos] = (j << 13) | ei_p[j];              // NP=8192 -> 13 src bits
    }
}

// ------- phase 4: atomic-free segmented reduce; h0 = x + mean(relu(x[src]+ea)) -------
__global__ __launch_bounds__(256) void node_aggr_kernel(
    const float* __restrict__ x_m, const float* __restrict__ ea_m,
    const int* __restrict__ start_m, const int* __restrict__ pidx_m,
    const float* __restrict__ x_p, const float* __restrict__ ea_p,
    const int* __restrict__ start_p, const int* __restrict__ pidx_p,
    float* __restrict__ h0_m, float* __restrict__ h0_p)
{
    int wave = threadIdx.x >> 6, lane = threadIdx.x & 63;
    int nid = blockIdx.x * 4 + wave;
    const float *x, *ea; const int *start, *pidx; float* h0; int n, sh, msk;
    if (nid < NM) { x = x_m; ea = ea_m; start = start_m; pidx = pidx_m; h0 = h0_m; n = nid; sh = 11; msk = 2047; }
    else          { x = x_p; ea = ea_p; start = start_p; pidx = pidx_p; h0 = h0_p; n = nid - NM; sh = 13; msk = 8191; }
    int b  = __builtin_amdgcn_readfirstlane(start[n]);
    int e  = __builtin_amdgcn_readfirstlane(start[n + 1]);
    int deg = e - b;
    const int* pp = pidx + b;
    float acc = 0.f;
    int j = 0;
    for (; j + 8 <= deg; j += 8) {
        int v0 = __builtin_amdgcn_readfirstlane(pp[j]);
        int v1 = __builtin_amdgcn_readfirstlane(pp[j + 1]);
        int v2 = __builtin_amdgcn_readfirstlane(pp[j + 2]);
        int v3 = __builtin_amdgcn_readfirstlane(pp[j + 3]);
        int v4 = __builtin_amdgcn_readfirstlane(pp[j + 4]);
        int v5 = __builtin_amdgcn_readfirstlane(pp[j + 5]);
        int v6 = __builtin_amdgcn_readfirstlane(pp[j + 6]);
        int v7 = __builtin_amdgcn_readfirstlane(pp[j + 7]);
        float a0 = ea[(size_t)(((unsigned)v0) >> sh) * 64 + lane];
        float a1 = ea[(size_t)(((unsigned)v1) >> sh) * 64 + lane];
        float a2 = ea[(size_t)(((unsigned)v2) >> sh) * 64 + lane];
        float a3 = ea[(size_t)(((unsigned)v3) >> sh) * 64 + lane];
        float a4 = ea[(size_t)(((unsigned)v4) >> sh) * 64 + lane];
        float a5 = ea[(size_t)(((unsigned)v5) >> sh) * 64 + lane];
        float a6 = ea[(size_t)(((unsigned)v6) >> sh) * 64 + lane];
        float a7 = ea[(size_t)(((unsigned)v7) >> sh) * 64 + lane];
        float y0 = x[(size_t)(v0 & msk) * 64 + lane];
        float y1 = x[(size_t)(v1 & msk) * 64 + lane];
        float y2 = x[(size_t)(v2 & msk) * 64 + lane];
        float y3 = x[(size_t)(v3 & msk) * 64 + lane];
        float y4 = x[(size_t)(v4 & msk) * 64 + lane];
        float y5 = x[(size_t)(v5 & msk) * 64 + lane];
        float y6 = x[(size_t)(v6 & msk) * 64 + lane];
        float y7 = x[(size_t)(v7 & msk) * 64 + lane];
        acc += fmaxf(y0 + a0, 0.f); acc += fmaxf(y1 + a1, 0.f);
        acc += fmaxf(y2 + a2, 0.f); acc += fmaxf(y3 + a3, 0.f);
        acc += fmaxf(y4 + a4, 0.f); acc += fmaxf(y5 + a5, 0.f);
        acc += fmaxf(y6 + a6, 0.f); acc += fmaxf(y7 + a7, 0.f);
    }
    for (; j < deg; ++j) {
        int v0 = __builtin_amdgcn_readfirstlane(pp[j]);
        acc += fmaxf(x[(size_t)(v0 & msk) * 64 + lane] + ea[(size_t)(((unsigned)v0) >> sh) * 64 + lane], 0.f);
    }
    float aggr = acc / fmaxf((float)deg, 1.f);
    h0[(size_t)n * 64 + lane] = x[(size_t)n * 64 + lane] + aggr;
}

// ------- fused GINE MLP + QKV (both graphs): one staging of rows, phased LDS weights -------
__global__ __launch_bounds__(256) void mlp_qkv_kernel(
    const float* __restrict__ h0_m, const float* __restrict__ h0_p,
    const float* __restrict__ w1m, const float* __restrict__ b1m,
    const float* __restrict__ w2m, const float* __restrict__ b2m,
    const float* __restrict__ w1p, const float* __restrict__ b1p,
    const float* __restrict__ w2p, const float* __restrict__ b2p,
    const float* __restrict__ wq_m, const float* __restrict__ bq_m,
    const float* __restrict__ wk_m, const float* __restrict__ bk_m,
    const float* __restrict__ wv_m, const float* __restrict__ bv_m,
    const float* __restrict__ wq_p, const float* __restrict__ bq_p,
    const float* __restrict__ wk_p, const float* __restrict__ bk_p,
    const float* __restrict__ wv_p, const float* __restrict__ bv_p,
    float* __restrict__ hm, float* __restrict__ hp,
    unsigned short* __restrict__ Qm, unsigned short* __restrict__ Km, unsigned short* __restrict__ Vtm,
    unsigned short* __restrict__ Qp, unsigned short* __restrict__ Kp, unsigned short* __restrict__ Vtp,
    int* __restrict__ norms)
{
    const float *h0, *w1, *b1, *w2, *b2, *wq, *bq, *wk, *bk, *wv, *bv;
    float* hout; unsigned short *Q, *K, *Vt; int row0, N, nbase;
    if (blockIdx.x < NM / 16) {
        h0 = h0_m; w1 = w1m; b1 = b1m; w2 = w2m; b2 = b2m;
        wq = wq_m; bq = bq_m; wk = wk_m; bk = bk_m; wv = wv_m; bv = bv_m;
        hout = hm; Q = Qm; K = Km; Vt = Vtm; N = NM; row0 = blockIdx.x * 16; nbase = 0;
    } else {
        h0 = h0_p; w1 = w1p; b1 = b1p; w2 = w2p; b2 = b2p;
        wq = wq_p; bq = bq_p; wk = wk_p; bk = bk_p; wv = wv_p; bv = bv_p;
        hout = hp; Q = Qp; K = Kp; Vt = Vtp; N = NP; row0 = (blockIdx.x - NM / 16) * 16; nbase = 2;
    }
    __shared__ float sWa[4096], sWb[4096], sWc[4096];
    __shared__ float sb1[64], sb2[64], sbq[64], sbk[64], sbv[64];
    __shared__ float sh0[16][64], sh1[16][64];
    __shared__ float rmx[8];
    int t = threadIdx.x;
    for (int i = t; i < 4096; i += 256) { sWa[i] = w1[i]; sWb[i] = w2[i]; sWc[i] = wq[i]; }
    if (t < 64) { sb1[t] = b1[t]; sb2[t] = b2[t]; sbq[t] = bq[t]; sbk[t] = bk[t]; sbv[t] = bv[t]; }
    for (int i = t; i < 16 * 64; i += 256) {
        int r = i >> 6, c = i & 63;
        sh0[r][c] = h0[(size_t)(row0 + r) * 64 + c];
    }
    __syncthreads();
    int j = t & 63, rs = t >> 6;
    // phase A: sh1 = relu(sh0 @ W1 + b1)
    for (int r = rs; r < 16; r += 4) {
        float a = sb1[j];
        #pragma unroll
        for (int c = 0; c < 64; c++) a += sh0[r][c] * sWa[c * 64 + j];
        sh1[r][j] = fmaxf(a, 0.0f);
    }
    __syncthreads();
    // phase B: h = relu(sh1 @ W2 + b2) -> global + sh0; reload sWa = Wk
    for (int r = rs; r < 16; r += 4) {
        float a = sb2[j];
        #pragma unroll
        for (int c = 0; c < 64; c++) a += sh1[r][c] * sWb[c * 64 + j];
        float hval = fmaxf(a, 0.0f);
        hout[(size_t)(row0 + r) * 64 + j] = hval;
        sh0[r][j] = hval;
    }
    for (int i = t; i < 4096; i += 256) sWa[i] = wk[i];
    __syncthreads();
    // phase C: Q (sWc), K (sWa) + norms; reload sWb = Wv
    float qmx = 0.f, kmx = 0.f;
    for (int r = rs; r < 16; r += 4) {
        float aq = sbq[j], ak = sbk[j];
        #pragma unroll
        for (int c = 0; c < 64; c++) {
            float h = sh0[r][c];
            aq += h * sWc[c * 64 + j];
            ak += h * sWa[c * 64 + j];
        }
        float qs = aq * (0.25f * LOG2E);      // fold 1/sqrt(HD) and log2(e)
        size_t o = (size_t)(row0 + r) * 64 + j;
        Q[o] = cvt_bf16(qs);
        K[o] = cvt_bf16(ak);
        float qsq = qs * qs, ksq = ak * ak;
        #pragma unroll
        for (int o2 = 1; o2 <= 8; o2 <<= 1) {
            qsq += __shfl_xor(qsq, o2, 64);
            ksq += __shfl_xor(ksq, o2, 64);
        }
        qmx = fmaxf(qmx, qsq);
        kmx = fmaxf(kmx, ksq);
    }
    for (int i = t; i < 4096; i += 256) sWb[i] = wv[i];
    qmx = fmaxf(qmx, __shfl_xor(qmx, 16, 64)); qmx = fmaxf(qmx, __shfl_xor(qmx, 32, 64));
    kmx = fmaxf(kmx, __shfl_xor(kmx, 16, 64)); kmx = fmaxf(kmx, __shfl_xor(kmx, 32, 64));
    if (j == 0) { rmx[rs] = qmx; rmx[4 + rs] = kmx; }
    __syncthreads();
    // phase D: V (transposed store)
    for (int r = rs; r < 16; r += 4) {
        float av = sbv[j];
        #pragma unroll
        for (int c = 0; c < 64; c++) av += sh0[r][c] * sWb[c * 64 + j];
        Vt[(size_t)j * N + row0 + r] = cvt_bf16(av);
    }
    if (t == 0) {
        float q4 = fmaxf(fmaxf(rmx[0], rmx[1]), fmaxf(rmx[2], rmx[3]));
        float k4 = fmaxf(fmaxf(rmx[4], rmx[5]), fmaxf(rmx[6], rmx[7]));
        atomicMax(&norms[nbase],     __float_as_int(sqrtf(q4)));
        atomicMax(&norms[nbase + 1], __float_as_int(sqrtf(k4)));
    }
}

// ------- MFMA flash-attention: fixed C-S bound m, 32 queries/wave, deferred-PV pipeline -------
// Manually unrolled in PAIRS so every buffer index is a compile-time constant
// (r9 lesson: dynamically-indexed register arrays fall to scratch). P double-buffered in
// LDS; the ds_read of iteration it-1's P issues a full exp/pack phase before its MFMA.
__global__ __launch_bounds__(256) void attn_kernel(
    const unsigned short* __restrict__ Qm, const unsigned short* __restrict__ Km,
    const unsigned short* __restrict__ Vtm,
    const unsigned short* __restrict__ Qp, const unsigned short* __restrict__ Kp,
    const unsigned short* __restrict__ Vtp,
    const int* __restrict__ norms, float* __restrict__ partial)
{
    __shared__ unsigned int plds[4][2][2][16][20];   // [wave][qtile][buf][qrow][16+pad]
    int t = threadIdx.x;
    int wave = t >> 6;
    int lane = t & 63;
    int qrow = lane & 15;
    int quad = lane >> 4;
    int W = blockIdx.x * 4 + wave;

    const unsigned short *Q, *K, *Vt; int Nk; float m;
    int chunk, h, qt2, Tbase, T1off;
    if (W < 2048) {
        Q = Qm; K = Kp; Vt = Vtp; Nk = NP;
        m = __int_as_float(norms[0]) * __int_as_float(norms[3]);
        chunk = W & 7; h = (W >> 3) & 3; qt2 = W >> 5;
        Tbase = W + qt2 * 32; T1off = 32;
    } else {
        int W2 = W - 2048;
        Q = Qp; K = Km; Vt = Vtm; Nk = NM;
        m = __int_as_float(norms[2]) * __int_as_float(norms[1]);
        chunk = W2 & 1; h = (W2 >> 1) & 3; qt2 = W2 >> 3;
        Tbase = 4096 + W2 + qt2 * 8; T1off = 8;
    }

    short8 qfA = {}, qfB = {};
    if (quad < 2) {
        qfA = *(const short8*)(Q + ((size_t)(qt2 * 32 + qrow)) * 64 + h * 16 + quad * 8);
        qfB = *(const short8*)(Q + ((size_t)(qt2 * 32 + 16 + qrow)) * 64 + h * 16 + quad * 8);
    }

    const f32x4 zero4 = {0.f, 0.f, 0.f, 0.f};
    int kbase = chunk * 1024;
    const unsigned short* krow = K + (size_t)(kbase + qrow) * 64 + h * 16 + quad * 8;
    const unsigned short* vrow = Vt + ((size_t)(h * 16 + qrow)) * Nk + kbase + quad * 8;

    float lA = 0.0f, lB = 0.0f;
    f32x4 accA = zero4, accB = zero4;

    short8 kf0_0, kf1_0, vf_0, kf0_1, kf1_1, vf_1;   // two prefetch slots, scalar names
    kf0_0 = (short8){}; kf1_0 = (short8){};
    kf0_1 = (short8){}; kf1_1 = (short8){};
    if (quad < 2) {
        kf0_0 = *(const short8*)(krow);
        kf1_0 = *(const short8*)(krow + 16 * 64);
        kf0_1 = *(const short8*)(krow + 32 * 64);
        kf1_1 = *(const short8*)(krow + 48 * 64);
    }
    vf_0 = *(const short8*)(vrow);
    vf_1 = *(const short8*)(vrow + 32);

    short8 vf_prev;

// QK + exp + pack + store-P to buffer BUF for iteration IT (slot SLOT = IT&1)
#define QK_PHASE(IT, SLOT, BUF)                                                             \
    {                                                                                       \
        short8 kf0 = kf0_##SLOT, kf1 = kf1_##SLOT, vf = vf_##SLOT;                          \
        if ((IT) < 30) {                                                                    \
            int off = ((IT) + 2) * 32;                                                      \
            if (quad < 2) {                                                                 \
                kf0_##SLOT = *(const short8*)(krow + (size_t)off * 64);                     \
                kf1_##SLOT = *(const short8*)(krow + (size_t)(off + 16) * 64);              \
            }                                                                               \
            vf_##SLOT = *(const short8*)(vrow + off);                                       \
        }                                                                                   \
        f32x4 s0A = __builtin_amdgcn_mfma_f32_16x16x32_bf16(kf0, qfA, zero4, 0, 0, 0);      \
        f32x4 s1A = __builtin_amdgcn_mfma_f32_16x16x32_bf16(kf1, qfA, zero4, 0, 0, 0);      \
        f32x4 s0B = __builtin_amdgcn_mfma_f32_16x16x32_bf16(kf0, qfB, zero4, 0, 0, 0);      \
        f32x4 s1B = __builtin_amdgcn_mfma_f32_16x16x32_bf16(kf1, qfB, zero4, 0, 0, 0);      \
        float a00 = e2(s0A.x - m), a01 = e2(s0A.y - m), a02 = e2(s0A.z - m), a03 = e2(s0A.w - m); \
        float a10 = e2(s1A.x - m), a11 = e2(s1A.y - m), a12 = e2(s1A.z - m), a13 = e2(s1A.w - m); \
        float b00 = e2(s0B.x - m), b01 = e2(s0B.y - m), b02 = e2(s0B.z - m), b03 = e2(s0B.w - m); \
        float b10 = e2(s1B.x - m), b11 = e2(s1B.y - m), b12 = e2(s1B.z - m), b13 = e2(s1B.w - m); \
        lA += (((a00 + a01) + (a02 + a03)) + ((a10 + a11) + (a12 + a13)));                  \
        lB += (((b00 + b01) + (b02 + b03)) + ((b10 + b11) + (b12 + b13)));                  \
        uint2 wA0; wA0.x = pk_bf16_tr(a00, a01); wA0.y = pk_bf16_tr(a02, a03);              \
        uint2 wA1; wA1.x = pk_bf16_tr(a10, a11); wA1.y = pk_bf16_tr(a12, a13);              \
        uint2 wB0; wB0.x = pk_bf16_tr(b00, b01); wB0.y = pk_bf16_tr(b02, b03);              \
        uint2 wB1; wB1.x = pk_bf16_tr(b10, b11); wB1.y = pk_bf16_tr(b12, b13);              \
        *(uint2*)&plds[wave][0][BUF][qrow][quad * 2] = wA0;                                 \
        *(uint2*)&plds[wave][0][BUF][qrow][8 + quad * 2] = wA1;                             \
        *(uint2*)&plds[wave][1][BUF][qrow][quad * 2] = wB0;                                 \
        *(uint2*)&plds[wave][1][BUF][qrow][8 + quad * 2] = wB1;                             \
        vf_cur = vf;                                                                        \
    }

// full pipelined step: early ds_read of P from buffer PREV, QK phase into BUF, then PV
#define STEP(IT, SLOT, BUF, PREV)                                                           \
    {                                                                                       \
        short8 pfA = *(short8*)&plds[wave][0][PREV][qrow][quad * 4];                        \
        short8 pfB = *(short8*)&plds[wave][1][PREV][qrow][quad * 4];                        \
        short8 vf_cur;                                                                      \
        QK_PHASE(IT, SLOT, BUF)                                                             \
        accA = __builtin_amdgcn_mfma_f32_16x16x32_bf16(vf_prev, pfA, accA, 0, 0, 0);        \
        accB = __builtin_amdgcn_mfma_f32_16x16x32_bf16(vf_prev, pfB, accB, 0, 0, 0);        \
        vf_prev = vf_cur;                                                                   \
    }

    // ---- it = 0 (peeled: QK + store P to buf0, no PV yet) ----
    {
        short8 vf_cur;
        QK_PHASE(0, 0, 0)
        vf_prev = vf_cur;
    }
    // ---- it = 1..30 in constant-index pairs ----
    for (int p = 0; p < 15; ++p) {
        int it1 = 2 * p + 1;
        STEP(it1, 1, 1, 0)
        STEP(it1 + 1, 0, 0, 1)
    }
    // ---- it = 31 ----
    STEP(31, 1, 1, 0)
    // ---- epilogue: PV for it=31's P (buffer 1) ----
    {
        short8 pfA = *(short8*)&plds[wave][0][1][qrow][quad * 4];
        short8 pfB = *(short8*)&plds[wave][1][1][qrow][quad * 4];
        accA = __builtin_amdgcn_mfma_f32_16x16x32_bf16(vf_prev, pfA, accA, 0, 0, 0);
        accB = __builtin_amdgcn_mfma_f32_16x16x32_bf16(vf_prev, pfB, accB, 0, 0, 0);
    }
#undef STEP
#undef QK_PHASE

    float ltA = lA + __shfl_xor(lA, 16, 64); ltA += __shfl_xor(ltA, 32, 64);
    float ltB = lB + __shfl_xor(lB, 16, 64); ltB += __shfl_xor(ltB, 32, 64);

    float* pb0 = partial + (size_t)Tbase * 288;
    *(f32x4*)&pb0[qrow * 16 + quad * 4] = accA;
    if (quad == 0) pb0[272 + qrow] = ltA;
    float* pb1 = partial + (size_t)(Tbase + T1off) * 288;
    *(f32x4*)&pb1[qrow * 16 + quad * 4] = accB;
    if (quad == 0) pb1[272 + qrow] = ltB;
}

// ------- merge chunk partials + residual + layernorm (uniform m: plain sums) -------
__global__ __launch_bounds__(256) void merge_ln_kernel(
    const float* __restrict__ partial,
    const float* __restrict__ h_m, const float* __restrict__ h_p,
    const float* __restrict__ gm, const float* __restrict__ bm,
    const float* __restrict__ gp, const float* __restrict__ bp_,
    float* __restrict__ out)
{
    int t = threadIdx.x;
    int grow = blockIdx.x * 4 + (t >> 6);
    int c = t & 63;
    const float *pbase, *hbuf, *g, *bb; float* o; int NC, row;
    if (grow < NM) { pbase = partial;               hbuf = h_m; g = gm; bb = bm;  o = out;             NC = 8; row = grow; }
    else           { pbase = partial + 4096 * 288;  hbuf = h_p; g = gp; bb = bp_; o = out + NM * 64;   NC = 2; row = grow - NM; }
    int hi = c >> 4, d = c & 15;
    int qt = row >> 4, ql = row & 15;
    const float* base = pbase + (size_t)(qt * 4 + hi) * NC * 288;
    float L = 0.0f, A = 0.0f;
    for (int cc = 0; cc < NC; ++cc) {
        L += base[cc * 288 + 272 + ql];
        A += base[cc * 288 + ql * 16 + d];
    }
    float v = hbuf[(size_t)row * 64 + c] + A / L;
    float s = v;
    #pragma unroll
    for (int o2 = 32; o2 >= 1; o2 >>= 1) s += __shfl_xor(s, o2, 64);
    float mu = s * (1.0f / 64.0f);
    float dv = v - mu;
    float sq = dv * dv;
    #pragma unroll
    for (int o2 = 32; o2 >= 1; o2 >>= 1) sq += __shfl_xor(sq, o2, 64);
    float var = sq * (1.0f / 64.0f);
    o[(size_t)row * 64 + c] = dv * rsqrtf(var + 1e-5f) * g[c] + bb[c];
}

extern "C" void kernel_launch(void* const* d_in, const int* in_sizes, int n_in,
                              void* d_out, int out_size, void* d_ws, size_t ws_size,
                              hipStream_t stream)
{
    const float* x_mol   = (const float*)d_in[0];
    const int*   ei_mol  = (const int*)  d_in[1];
    const float* ea_mol  = (const float*)d_in[2];
    const float* x_prot  = (const float*)d_in[3];
    const int*   ei_prot = (const int*)  d_in[4];
    const float* ea_prot = (const float*)d_in[5];
    const float* mol_w1  = (const float*)d_in[6];
    const float* mol_b1  = (const float*)d_in[7];
    const float* mol_w2  = (const float*)d_in[8];
    const float* mol_b2  = (const float*)d_in[9];
    const float* prot_w1 = (const float*)d_in[10];
    const float* prot_b1 = (const float*)d_in[11];
    const float* prot_w2 = (const float*)d_in[12];
    const float* prot_b2 = (const float*)d_in[13];
    const float* mp_wq = (const float*)d_in[14]; const float* mp_bq = (const float*)d_in[15];
    const float* mp_wk = (const float*)d_in[16]; const float* mp_bk = (const float*)d_in[17];
    const float* mp_wv = (const float*)d_in[18]; const float* mp_bv = (const float*)d_in[19];
    const float* pm_wq = (const float*)d_in[20]; const float* pm_bq = (const float*)d_in[21];
    const float* pm_wk = (const float*)d_in[22]; const float* pm_bk = (const float*)d_in[23];
    const float* pm_wv = (const float*)d_in[24]; const float* pm_bv = (const float*)d_in[25];
    const float* ln_mol_g  = (const float*)d_in[26];
    const float* ln_mol_b  = (const float*)d_in[27];
    const float* ln_prot_g = (const float*)d_in[28];
    const float* ln_prot_b = (const float*)d_in[29];

    float* ws = (float*)d_ws;
    // float region
    float* h_mol   = ws;                         // 131072
    float* h_prot  = h_mol + 131072;             // 524288
    float* partial = h_prot + 524288;            // 8192*288 (mol tasks 0..4095, prot 4096..8191)
    float* h0_mol  = partial;                    // alias: dead before attn writes
    float* h0_prot = h0_mol + 131072;
    // int region
    int* ip      = (int*)(partial + 2359296);
    int* cnt_m   = ip;                 // 2048
    int* cnt_p   = cnt_m + 2048;       // 8192
    int* norms   = cnt_p + 8192;       // 4  (0=Qm,1=Km,2=Qp,3=Kp; float bits)
    int* start_m = norms + 4;          // 2052 (2049 used)
    int* start_p = start_m + 2052;     // 8196 (8193 used)
    int* cur_m   = start_p + 8196;     // 2048
    int* cur_p   = cur_m + 2048;       // 8192
    int* pidx_m  = cur_p + 8192;       // 32768
    int* pidx_p  = pidx_m + 32768;     // 262144
    // bf16 region; K arrays not region-last (prefetch may read 32 rows past chunk end)
    unsigned short* bf = (unsigned short*)(pidx_p + 262144);
    unsigned short* Qm  = bf;            // 131072
    unsigned short* Km  = Qm + 131072;   // 131072  (followed by Vtm: OOB-safe)
    unsigned short* Vtm = Km + 131072;   // 131072  [64][NM]
    unsigned short* Qp  = Vtm + 131072;  // 524288
    unsigned short* Kp  = Qp + 524288;   // 524288  (followed by Vtp: OOB-safe)
    unsigned short* Vtp = Kp + 524288;   // 524288  [64][NP]

    hipMemsetAsync(cnt_m, 0, (size_t)(2048 + 8192 + 4) * sizeof(int), stream);

    const int EB = (EM + EP) / 256;   // 1152
    hist_kernel<<<EB, 256, 0, stream>>>(ei_mol, ei_prot, cnt_m, cnt_p);
    scan_kernel<<<2, 256, 0, stream>>>(cnt_m, cnt_p, start_m, start_p, cur_m, cur_p);
    scatter_kernel<<<EB, 256, 0, stream>>>(ei_mol, ei_prot, cur_m, cur_p, pidx_m, pidx_p);
    node_aggr_kernel<<<(NM + NP) / 4, 256, 0, stream>>>(
        x_mol, ea_mol, start_m, pidx_m,
        x_prot, ea_prot, start_p, pidx_p, h0_mol, h0_prot);

    mlp_qkv_kernel<<<(NM + NP) / 16, 256, 0, stream>>>(
        h0_mol, h0_prot,
        mol_w1, mol_b1, mol_w2, mol_b2, prot_w1, prot_b1, prot_w2, prot_b2,
        mp_wq, mp_bq, pm_wk, pm_bk, pm_wv, pm_bv,
        pm_wq, pm_bq, mp_wk, mp_bk, mp_wv, mp_bv,
        h_mol, h_prot, Qm, Km, Vtm, Qp, Kp, Vtp, norms);

    // both directions, 32 queries/wave: 1024 blocks x 4 waves = 4096 tasks
    attn_kernel<<<1024, 256, 0, stream>>>(Qm, Km, Vtm, Qp, Kp, Vtp, norms, partial);

    float* out = (float*)d_out;
    merge_ln_kernel<<<(NM + NP) / 4, 256, 0, stream>>>(
        partial, h_mol, h_prot, ln_mol_g, ln_mol_b, ln_prot_g, ln_prot_b, out);
}

// Round 11
// 294.097 us; speedup vs baseline: 2.1434x; 1.0318x over previous
//
#include <hip/hip_runtime.h>

#define NM 2048
#define EM 32768
#define NP 8192
#define EP 262144

typedef __attribute__((ext_vector_type(8))) short short8;
typedef __attribute__((ext_vector_type(4))) float f32x4;
typedef __attribute__((ext_vector_type(16))) float f32x16;

#define LOG2E 1.44269504088896340736f

__device__ __forceinline__ float e2(float x) { return __builtin_amdgcn_exp2f(x); }
// pack two fp32 -> bf16x2 by TRUNCATION (1 inst); P in [0,1], validated r7/r8 (absmax 0.031)
__device__ __forceinline__ unsigned int pk_bf16_tr(float a, float b) {
    return __builtin_amdgcn_perm(__float_as_uint(a), __float_as_uint(b), 0x03020706u);
}
__device__ __forceinline__ unsigned short cvt_bf16(float f) {
    unsigned int u = __float_as_uint(f);
    u = (u + 0x7fff + ((u >> 16) & 1)) >> 16;   // RNE
    return (unsigned short)u;
}

// ---------------- phase 1: histogram of dst (both graphs) ----------------
__global__ __launch_bounds__(256) void hist_kernel(
    const int* __restrict__ ei_m, const int* __restrict__ ei_p,
    int* __restrict__ cnt_m, int* __restrict__ cnt_p)
{
    int idx = blockIdx.x * 256 + threadIdx.x;
    if (idx < EM) atomicAdd(&cnt_m[ei_m[EM + idx]], 1);
    int j = idx - EM;
    if (j >= 0 && j < EP) atomicAdd(&cnt_p[ei_p[EP + j]], 1);
}

// ---------------- phase 2: exclusive prefix sum (block 0 = mol, block 1 = prot) ----------------
__global__ __launch_bounds__(256) void scan_kernel(
    const int* __restrict__ cnt_m, const int* __restrict__ cnt_p,
    int* __restrict__ start_m, int* __restrict__ start_p,
    int* __restrict__ cur_m, int* __restrict__ cur_p)
{
    const int* cnt; int* start; int* cur; int n;
    if (blockIdx.x == 0) { cnt = cnt_m; start = start_m; cur = cur_m; n = NM; }
    else                 { cnt = cnt_p; start = start_p; cur = cur_p; n = NP; }
    int per = n >> 8;
    int tid = threadIdx.x;
    int base = tid * per;
    int s = 0;
    for (int i = 0; i < per; i++) s += cnt[base + i];
    __shared__ int wsum[4];
    int lane = tid & 63, w = tid >> 6;
    int v = s;
    #pragma unroll
    for (int off = 1; off < 64; off <<= 1) {
        int u = __shfl_up(v, off, 64);
        if (lane >= off) v += u;
    }
    if (lane == 63) wsum[w] = v;
    __syncthreads();
    int wo = 0;
    for (int i = 0; i < w; i++) wo += wsum[i];
    int run = wo + v - s;   // exclusive prefix for this thread's range
    for (int i = 0; i < per; i++) {
        start[base + i] = run; cur[base + i] = run;
        run += cnt[base + i];
    }
    if (tid == 255) start[n] = run;
}

// ------- phase 3: scatter packed (edge<<sh)|src into dst-sorted order -------
__global__ __launch_bounds__(256) void scatter_kernel(
    const int* __restrict__ ei_m, const int* __restrict__ ei_p,
    int* __restrict__ cur_m, int* __restrict__ cur_p,
    int* __restrict__ pidx_m, int* __restrict__ pidx_p)
{
    int idx = blockIdx.x * 256 + threadIdx.x;
    if (idx < EM) {
        int d = ei_m[EM + idx];
        int pos = atomicAdd(&cur_m[d], 1);
        pidx_m[pos] = (idx << 11) | ei_m[idx];          // NM=2048 -> 11 src bits
    }
    int j = idx - EM;
    if (j >= 0 && j < EP) {
        int d = ei_p[EP + j];
        int pos = atomicAdd(&cur_p[d], 1);
        pidx_p[pos] = (j << 13) | ei_p[j];              // NP=8192 -> 13 src bits
    }
}

// ------- phase 4: atomic-free segmented reduce; h0 = x + mean(relu(x[src]+ea)) -------
__global__ __launch_bounds__(256) void node_aggr_kernel(
    const float* __restrict__ x_m, const float* __restrict__ ea_m,
    const int* __restrict__ start_m, const int* __restrict__ pidx_m,
    const float* __restrict__ x_p, const float* __restrict__ ea_p,
    const int* __restrict__ start_p, const int* __restrict__ pidx_p,
    float* __restrict__ h0_m, float* __restrict__ h0_p)
{
    int wave = threadIdx.x >> 6, lane = threadIdx.x & 63;
    int nid = blockIdx.x * 4 + wave;
    const float *x, *ea; const int *start, *pidx; float* h0; int n, sh, msk;
    if (nid < NM) { x = x_m; ea = ea_m; start = start_m; pidx = pidx_m; h0 = h0_m; n = nid; sh = 11; msk = 2047; }
    else          { x = x_p; ea = ea_p; start = start_p; pidx = pidx_p; h0 = h0_p; n = nid - NM; sh = 13; msk = 8191; }
    int b  = __builtin_amdgcn_readfirstlane(start[n]);
    int e  = __builtin_amdgcn_readfirstlane(start[n + 1]);
    int deg = e - b;
    const int* pp = pidx + b;
    float acc = 0.f;
    int j = 0;
    for (; j + 8 <= deg; j += 8) {
        int v0 = __builtin_amdgcn_readfirstlane(pp[j]);
        int v1 = __builtin_amdgcn_readfirstlane(pp[j + 1]);
        int v2 = __builtin_amdgcn_readfirstlane(pp[j + 2]);
        int v3 = __builtin_amdgcn_readfirstlane(pp[j + 3]);
        int v4 = __builtin_amdgcn_readfirstlane(pp[j + 4]);
        int v5 = __builtin_amdgcn_readfirstlane(pp[j + 5]);
        int v6 = __builtin_amdgcn_readfirstlane(pp[j + 6]);
        int v7 = __builtin_amdgcn_readfirstlane(pp[j + 7]);
        float a0 = ea[(size_t)(((unsigned)v0) >> sh) * 64 + lane];
        float a1 = ea[(size_t)(((unsigned)v1) >> sh) * 64 + lane];
        float a2 = ea[(size_t)(((unsigned)v2) >> sh) * 64 + lane];
        float a3 = ea[(size_t)(((unsigned)v3) >> sh) * 64 + lane];
        float a4 = ea[(size_t)(((unsigned)v4) >> sh) * 64 + lane];
        float a5 = ea[(size_t)(((unsigned)v5) >> sh) * 64 + lane];
        float a6 = ea[(size_t)(((unsigned)v6) >> sh) * 64 + lane];
        float a7 = ea[(size_t)(((unsigned)v7) >> sh) * 64 + lane];
        float y0 = x[(size_t)(v0 & msk) * 64 + lane];
        float y1 = x[(size_t)(v1 & msk) * 64 + lane];
        float y2 = x[(size_t)(v2 & msk) * 64 + lane];
        float y3 = x[(size_t)(v3 & msk) * 64 + lane];
        float y4 = x[(size_t)(v4 & msk) * 64 + lane];
        float y5 = x[(size_t)(v5 & msk) * 64 + lane];
        float y6 = x[(size_t)(v6 & msk) * 64 + lane];
        float y7 = x[(size_t)(v7 & msk) * 64 + lane];
        acc += fmaxf(y0 + a0, 0.f); acc += fmaxf(y1 + a1, 0.f);
        acc += fmaxf(y2 + a2, 0.f); acc += fmaxf(y3 + a3, 0.f);
        acc += fmaxf(y4 + a4, 0.f); acc += fmaxf(y5 + a5, 0.f);
        acc += fmaxf(y6 + a6, 0.f); acc += fmaxf(y7 + a7, 0.f);
    }
    for (; j < deg; ++j) {
        int v0 = __builtin_amdgcn_readfirstlane(pp[j]);
        acc += fmaxf(x[(size_t)(v0 & msk) * 64 + lane] + ea[(size_t)(((unsigned)v0) >> sh) * 64 + lane], 0.f);
    }
    float aggr = acc / fmaxf((float)deg, 1.f);
    h0[(size_t)n * 64 + lane] = x[(size_t)n * 64 + lane] + aggr;
}

// ------- fused GINE MLP + QKV (both graphs): 32 rows/block, phased LDS weights -------
__global__ __launch_bounds__(256) void mlp_qkv_kernel(
    const float* __restrict__ h0_m, const float* __restrict__ h0_p,
    const float* __restrict__ w1m, const float* __restrict__ b1m,
    const float* __restrict__ w2m, const float* __restrict__ b2m,
    const float* __restrict__ w1p, const float* __restrict__ b1p,
    const float* __restrict__ w2p, const float* __restrict__ b2p,
    const float* __restrict__ wq_m, const float* __restrict__ bq_m,
    const float* __restrict__ wk_m, const float* __restrict__ bk_m,
    const float* __restrict__ wv_m, const float* __restrict__ bv_m,
    const float* __restrict__ wq_p, const float* __restrict__ bq_p,
    const float* __restrict__ wk_p, const float* __restrict__ bk_p,
    const float* __restrict__ wv_p, const float* __restrict__ bv_p,
    float* __restrict__ hm, float* __restrict__ hp,
    unsigned short* __restrict__ Qm, unsigned short* __restrict__ Km, unsigned short* __restrict__ Vtm,
    unsigned short* __restrict__ Qp, unsigned short* __restrict__ Kp, unsigned short* __restrict__ Vtp,
    int* __restrict__ norms)
{
    const float *h0, *w1, *b1, *w2, *b2, *wq, *bq, *wk, *bk, *wv, *bv;
    float* hout; unsigned short *Q, *K, *Vt; int row0, N, nbase;
    if (blockIdx.x < NM / 32) {
        h0 = h0_m; w1 = w1m; b1 = b1m; w2 = w2m; b2 = b2m;
        wq = wq_m; bq = bq_m; wk = wk_m; bk = bk_m; wv = wv_m; bv = bv_m;
        hout = hm; Q = Qm; K = Km; Vt = Vtm; N = NM; row0 = blockIdx.x * 32; nbase = 0;
    } else {
        h0 = h0_p; w1 = w1p; b1 = b1p; w2 = w2p; b2 = b2p;
        wq = wq_p; bq = bq_p; wk = wk_p; bk = bk_p; wv = wv_p; bv = bv_p;
        hout = hp; Q = Qp; K = Kp; Vt = Vtp; N = NP; row0 = (blockIdx.x - NM / 32) * 32; nbase = 2;
    }
    __shared__ float sWa[4096], sWb[4096], sWc[4096];
    __shared__ float sb1[64], sb2[64], sbq[64], sbk[64], sbv[64];
    __shared__ float sh0[32][64], sh1[32][64];
    __shared__ float rmx[8];
    int t = threadIdx.x;
    for (int i = t; i < 4096; i += 256) { sWa[i] = w1[i]; sWb[i] = w2[i]; sWc[i] = wq[i]; }
    if (t < 64) { sb1[t] = b1[t]; sb2[t] = b2[t]; sbq[t] = bq[t]; sbk[t] = bk[t]; sbv[t] = bv[t]; }
    for (int i = t; i < 32 * 64; i += 256) {
        int r = i >> 6, c = i & 63;
        sh0[r][c] = h0[(size_t)(row0 + r) * 64 + c];
    }
    __syncthreads();
    int j = t & 63, rs = t >> 6;
    // phase A: sh1 = relu(sh0 @ W1 + b1)
    for (int r = rs; r < 32; r += 4) {
        float a = sb1[j];
        #pragma unroll
        for (int c = 0; c < 64; c++) a += sh0[r][c] * sWa[c * 64 + j];
        sh1[r][j] = fmaxf(a, 0.0f);
    }
    __syncthreads();
    // phase B: h = relu(sh1 @ W2 + b2) -> global + sh0; reload sWa = Wk
    for (int r = rs; r < 32; r += 4) {
        float a = sb2[j];
        #pragma unroll
        for (int c = 0; c < 64; c++) a += sh1[r][c] * sWb[c * 64 + j];
        float hval = fmaxf(a, 0.0f);
        hout[(size_t)(row0 + r) * 64 + j] = hval;
        sh0[r][j] = hval;
    }
    for (int i = t; i < 4096; i += 256) sWa[i] = wk[i];
    __syncthreads();
    // phase C: Q (sWc), K (sWa) + norms; reload sWb = Wv
    float qmx = 0.f, kmx = 0.f;
    for (int r = rs; r < 32; r += 4) {
        float aq = sbq[j], ak = sbk[j];
        #pragma unroll
        for (int c = 0; c < 64; c++) {
            float h = sh0[r][c];
            aq += h * sWc[c * 64 + j];
            ak += h * sWa[c * 64 + j];
        }
        float qs = aq * (0.25f * LOG2E);      // fold 1/sqrt(HD) and log2(e)
        size_t o = (size_t)(row0 + r) * 64 + j;
        Q[o] = cvt_bf16(qs);
        K[o] = cvt_bf16(ak);
        float qsq = qs * qs, ksq = ak * ak;
        #pragma unroll
        for (int o2 = 1; o2 <= 8; o2 <<= 1) {
            qsq += __shfl_xor(qsq, o2, 64);
            ksq += __shfl_xor(ksq, o2, 64);
        }
        qmx = fmaxf(qmx, qsq);
        kmx = fmaxf(kmx, ksq);
    }
    for (int i = t; i < 4096; i += 256) sWb[i] = wv[i];
    qmx = fmaxf(qmx, __shfl_xor(qmx, 16, 64)); qmx = fmaxf(qmx, __shfl_xor(qmx, 32, 64));
    kmx = fmaxf(kmx, __shfl_xor(kmx, 16, 64)); kmx = fmaxf(kmx, __shfl_xor(kmx, 32, 64));
    if (j == 0) { rmx[rs] = qmx; rmx[4 + rs] = kmx; }
    __syncthreads();
    // phase D: V (transposed store)
    for (int r = rs; r < 32; r += 4) {
        float av = sbv[j];
        #pragma unroll
        for (int c = 0; c < 64; c++) av += sh0[r][c] * sWb[c * 64 + j];
        Vt[(size_t)j * N + row0 + r] = cvt_bf16(av);
    }
    if (t == 0) {
        float q4 = fmaxf(fmaxf(rmx[0], rmx[1]), fmaxf(rmx[2], rmx[3]));
        float k4 = fmaxf(fmaxf(rmx[4], rmx[5]), fmaxf(rmx[6], rmx[7]));
        atomicMax(&norms[nbase],     __float_as_int(sqrtf(q4)));
        atomicMax(&norms[nbase + 1], __float_as_int(sqrtf(k4)));
    }
}

// ------- MFMA flash-attention: 32x32x16 QK (K=16 == HD, no padding), fixed C-S bound m -------
// One 32x32x16 MFMA yields the full 32-key x 32-query score tile: lane holds q=lane&31,
// keys (r&3)+8*(r>>2)+4*(lane>>5). P -> LDS in the (validated) 16x16x32 B-layout slots;
// PV consumer unchanged. Deferred-PV pipeline with constant-index pair unroll (r9 lesson).
__global__ __launch_bounds__(256) void attn_kernel(
    const unsigned short* __restrict__ Qm, const unsigned short* __restrict__ Km,
    const unsigned short* __restrict__ Vtm,
    const unsigned short* __restrict__ Qp, const unsigned short* __restrict__ Kp,
    const unsigned short* __restrict__ Vtp,
    const int* __restrict__ norms, float* __restrict__ partial)
{
    __shared__ unsigned int plds[4][2][2][16][20];   // [wave][qtile][buf][qrow][16+pad]
    int t = threadIdx.x;
    int wave = t >> 6;
    int lane = t & 63;
    int qrow = lane & 15;     // PV consumer / acc indices
    int quad = lane >> 4;
    int q5   = lane & 31;     // QK producer: this lane's query
    int half = lane >> 5;     // QK producer: key-half selector
    int qtl  = q5 >> 4;       // producer qtile
    int dwb  = half * 2;      // producer dword base in P rows
    int W = blockIdx.x * 4 + wave;

    const unsigned short *Q, *K, *Vt; int Nk; float m;
    int chunk, h, qt2, Tbase, T1off;
    if (W < 2048) {
        Q = Qm; K = Kp; Vt = Vtp; Nk = NP;
        m = __int_as_float(norms[0]) * __int_as_float(norms[3]);
        chunk = W & 7; h = (W >> 3) & 3; qt2 = W >> 5;
        Tbase = W + qt2 * 32; T1off = 32;
    } else {
        int W2 = W - 2048;
        Q = Qp; K = Km; Vt = Vtm; Nk = NM;
        m = __int_as_float(norms[2]) * __int_as_float(norms[1]);
        chunk = W2 & 1; h = (W2 >> 1) & 3; qt2 = W2 >> 3;
        Tbase = 4096 + W2 + qt2 * 8; T1off = 8;
    }

    // B operand of 32x32x16 QK: B[k=half*8+j][n=q5] = Q[q][dim] — all 64 lanes useful
    short8 qf = *(const short8*)(Q + ((size_t)(qt2 * 32 + q5)) * 64 + h * 16 + half * 8);

    const f32x16 zero16 = {0.f,0.f,0.f,0.f,0.f,0.f,0.f,0.f,0.f,0.f,0.f,0.f,0.f,0.f,0.f,0.f};
    const f32x4 zero4 = {0.f, 0.f, 0.f, 0.f};
    int kbase = chunk * 1024;
    // A operand of QK: A[m=key=q5][k=half*8+j] — no masking
    const unsigned short* krow = K + (size_t)(kbase + q5) * 64 + h * 16 + half * 8;
    // A operand of PV: A[m=d=qrow][k=quad*8+j]
    const unsigned short* vrow = Vt + ((size_t)(h * 16 + qrow)) * Nk + kbase + quad * 8;

    float l = 0.0f;
    f32x4 accA = zero4, accB = zero4;

    short8 kf_0, kf_1, vf_0, vf_1;   // two prefetch slots, scalar names (constant-indexed)
    kf_0 = *(const short8*)(krow);
    kf_1 = *(const short8*)(krow + 32 * 64);
    vf_0 = *(const short8*)(vrow);
    vf_1 = *(const short8*)(vrow + 32);

    short8 vf_prev;

// QK (32x32x16) + exp + pack + store-P to buffer BUF for iteration IT (slot SLOT = IT&1)
#define QK_PHASE(IT, SLOT, BUF)                                                             \
    {                                                                                       \
        short8 kf = kf_##SLOT; short8 vf = vf_##SLOT;                                       \
        if ((IT) < 30) {                                                                    \
            int off = ((IT) + 2) * 32;                                                      \
            kf_##SLOT = *(const short8*)(krow + (size_t)off * 64);                          \
            vf_##SLOT = *(const short8*)(vrow + off);                                       \
        }                                                                                   \
        f32x16 s = __builtin_amdgcn_mfma_f32_32x32x16_bf16(kf, qf, zero16, 0, 0, 0);        \
        float p0  = e2(s[0] - m),  p1  = e2(s[1] - m),  p2  = e2(s[2] - m),  p3  = e2(s[3] - m);  \
        float p4  = e2(s[4] - m),  p5  = e2(s[5] - m),  p6  = e2(s[6] - m),  p7  = e2(s[7] - m);  \
        float p8  = e2(s[8] - m),  p9  = e2(s[9] - m),  p10 = e2(s[10] - m), p11 = e2(s[11] - m); \
        float p12 = e2(s[12] - m), p13 = e2(s[13] - m), p14 = e2(s[14] - m), p15 = e2(s[15] - m); \
        l += (((p0 + p1) + (p2 + p3)) + ((p4 + p5) + (p6 + p7)))                            \
           + (((p8 + p9) + (p10 + p11)) + ((p12 + p13) + (p14 + p15)));                     \
        uint2 w0; w0.x = pk_bf16_tr(p0, p1);   w0.y = pk_bf16_tr(p2, p3);                   \
        uint2 w1; w1.x = pk_bf16_tr(p4, p5);   w1.y = pk_bf16_tr(p6, p7);                   \
        uint2 w2; w2.x = pk_bf16_tr(p8, p9);   w2.y = pk_bf16_tr(p10, p11);                 \
        uint2 w3; w3.x = pk_bf16_tr(p12, p13); w3.y = pk_bf16_tr(p14, p15);                 \
        *(uint2*)&plds[wave][qtl][BUF][qrow][dwb]      = w0;                                \
        *(uint2*)&plds[wave][qtl][BUF][qrow][dwb + 4]  = w1;                                \
        *(uint2*)&plds[wave][qtl][BUF][qrow][dwb + 8]  = w2;                                \
        *(uint2*)&plds[wave][qtl][BUF][qrow][dwb + 12] = w3;                                \
        vf_cur = vf;                                                                        \
    }

// full pipelined step: early ds_read of P from buffer PREV, QK phase into BUF, then PV
#define STEP(IT, SLOT, BUF, PREV)                                                           \
    {                                                                                       \
        short8 pfA = *(short8*)&plds[wave][0][PREV][qrow][quad * 4];                        \
        short8 pfB = *(short8*)&plds[wave][1][PREV][qrow][quad * 4];                        \
        short8 vf_cur;                                                                      \
        QK_PHASE(IT, SLOT, BUF)                                                             \
        accA = __builtin_amdgcn_mfma_f32_16x16x32_bf16(vf_prev, pfA, accA, 0, 0, 0);        \
        accB = __builtin_amdgcn_mfma_f32_16x16x32_bf16(vf_prev, pfB, accB, 0, 0, 0);        \
        vf_prev = vf_cur;                                                                   \
    }

    // ---- it = 0 (peeled: QK + store P to buf0, no PV yet) ----
    {
        short8 vf_cur;
        QK_PHASE(0, 0, 0)
        vf_prev = vf_cur;
    }
    // ---- it = 1..30 in constant-index pairs ----
    for (int p = 0; p < 15; ++p) {
        STEP(2 * p + 1, 1, 1, 0)
        STEP(2 * p + 2, 0, 0, 1)
    }
    // ---- it = 31 ----
    STEP(31, 1, 1, 0)
    // ---- epilogue: PV for it=31's P (buffer 1) ----
    {
        short8 pfA = *(short8*)&plds[wave][0][1][qrow][quad * 4];
        short8 pfB = *(short8*)&plds[wave][1][1][qrow][quad * 4];
        accA = __builtin_amdgcn_mfma_f32_16x16x32_bf16(vf_prev, pfA, accA, 0, 0, 0);
        accB = __builtin_amdgcn_mfma_f32_16x16x32_bf16(vf_prev, pfB, accB, 0, 0, 0);
    }
#undef STEP
#undef QK_PHASE

    // lane L holds l for q=L&31 over its key-half; combine halves
    float ltot = l + __shfl_xor(l, 32, 64);

    float* pb0 = partial + (size_t)Tbase * 288;
    *(f32x4*)&pb0[qrow * 16 + quad * 4] = accA;
    float* pb1 = partial + (size_t)(Tbase + T1off) * 288;
    *(f32x4*)&pb1[qrow * 16 + quad * 4] = accB;
    if (lane < 16)       pb0[272 + q5] = ltot;
    else if (lane < 32)  pb1[272 + (q5 - 16)] = ltot;
}

// ------- merge chunk partials + residual + layernorm (uniform m: plain sums) -------
__global__ __launch_bounds__(256) void merge_ln_kernel(
    const float* __restrict__ partial,
    const float* __restrict__ h_m, const float* __restrict__ h_p,
    const float* __restrict__ gm, const float* __restrict__ bm,
    const float* __restrict__ gp, const float* __restrict__ bp_,
    float* __restrict__ out)
{
    int t = threadIdx.x;
    int grow = blockIdx.x * 4 + (t >> 6);
    int c = t & 63;
    const float *pbase, *hbuf, *g, *bb; float* o; int NC, row;
    if (grow < NM) { pbase = partial;               hbuf = h_m; g = gm; bb = bm;  o = out;             NC = 8; row = grow; }
    else           { pbase = partial + 4096 * 288;  hbuf = h_p; g = gp; bb = bp_; o = out + NM * 64;   NC = 2; row = grow - NM; }
    int hi = c >> 4, d = c & 15;
    int qt = row >> 4, ql = row & 15;
    const float* base = pbase + (size_t)(qt * 4 + hi) * NC * 288;
    float L = 0.0f, A = 0.0f;
    for (int cc = 0; cc < NC; ++cc) {
        L += base[cc * 288 + 272 + ql];
        A += base[cc * 288 + ql * 16 + d];
    }
    float v = hbuf[(size_t)row * 64 + c] + A / L;
    float s = v;
    #pragma unroll
    for (int o2 = 32; o2 >= 1; o2 >>= 1) s += __shfl_xor(s, o2, 64);
    float mu = s * (1.0f / 64.0f);
    float dv = v - mu;
    float sq = dv * dv;
    #pragma unroll
    for (int o2 = 32; o2 >= 1; o2 >>= 1) sq += __shfl_xor(sq, o2, 64);
    float var = sq * (1.0f / 64.0f);
    o[(size_t)row * 64 + c] = dv * rsqrtf(var + 1e-5f) * g[c] + bb[c];
}

extern "C" void kernel_launch(void* const* d_in, const int* in_sizes, int n_in,
                              void* d_out, int out_size, void* d_ws, size_t ws_size,
                              hipStream_t stream)
{
    const float* x_mol   = (const float*)d_in[0];
    const int*   ei_mol  = (const int*)  d_in[1];
    const float* ea_mol  = (const float*)d_in[2];
    const float* x_prot  = (const float*)d_in[3];
    const int*   ei_prot = (const int*)  d_in[4];
    const float* ea_prot = (const float*)d_in[5];
    const float* mol_w1  = (const float*)d_in[6];
    const float* mol_b1  = (const float*)d_in[7];
    const float* mol_w2  = (const float*)d_in[8];
    const float* mol_b2  = (const float*)d_in[9];
    const float* prot_w1 = (const float*)d_in[10];
    const float* prot_b1 = (const float*)d_in[11];
    const float* prot_w2 = (const float*)d_in[12];
    const float* prot_b2 = (const float*)d_in[13];
    const float* mp_wq = (const float*)d_in[14]; const float* mp_bq = (const float*)d_in[15];
    const float* mp_wk = (const float*)d_in[16]; const float* mp_bk = (const float*)d_in[17];
    const float* mp_wv = (const float*)d_in[18]; const float* mp_bv = (const float*)d_in[19];
    const float* pm_wq = (const float*)d_in[20]; const float* pm_bq = (const float*)d_in[21];
    const float* pm_wk = (const float*)d_in[22]; const float* pm_bk = (const float*)d_in[23];
    const float* pm_wv = (const float*)d_in[24]; const float* pm_bv = (const float*)d_in[25];
    const float* ln_mol_g  = (const float*)d_in[26];
    const float* ln_mol_b  = (const float*)d_in[27];
    const float* ln_prot_g = (const float*)d_in[28];
    const float* ln_prot_b = (const float*)d_in[29];

    float* ws = (float*)d_ws;
    // float region
    float* h_mol   = ws;                         // 131072
    float* h_prot  = h_mol + 131072;             // 524288
    float* partial = h_prot + 524288;            // 8192*288 (mol tasks 0..4095, prot 4096..8191)
    float* h0_mol  = partial;                    // alias: dead before attn writes
    float* h0_prot = h0_mol + 131072;
    // int region
    int* ip      = (int*)(partial + 2359296);
    int* cnt_m   = ip;                 // 2048
    int* cnt_p   = cnt_m + 2048;       // 8192
    int* norms   = cnt_p + 8192;       // 4  (0=Qm,1=Km,2=Qp,3=Kp; float bits)
    int* start_m = norms + 4;          // 2052 (2049 used)
    int* start_p = start_m + 2052;     // 8196 (8193 used)
    int* cur_m   = start_p + 8196;     // 2048
    int* cur_p   = cur_m + 2048;       // 8192
    int* pidx_m  = cur_p + 8192;       // 32768
    int* pidx_p  = pidx_m + 32768;     // 262144
    // bf16 region
    unsigned short* bf = (unsigned short*)(pidx_p + 262144);
    unsigned short* Qm  = bf;            // 131072
    unsigned short* Km  = Qm + 131072;   // 131072
    unsigned short* Vtm = Km + 131072;   // 131072  [64][NM]
    unsigned short* Qp  = Vtm + 131072;  // 524288
    unsigned short* Kp  = Qp + 524288;   // 524288
    unsigned short* Vtp = Kp + 524288;   // 524288  [64][NP]

    hipMemsetAsync(cnt_m, 0, (size_t)(2048 + 8192 + 4) * sizeof(int), stream);

    const int EB = (EM + EP) / 256;   // 1152
    hist_kernel<<<EB, 256, 0, stream>>>(ei_mol, ei_prot, cnt_m, cnt_p);
    scan_kernel<<<2, 256, 0, stream>>>(cnt_m, cnt_p, start_m, start_p, cur_m, cur_p);
    scatter_kernel<<<EB, 256, 0, stream>>>(ei_mol, ei_prot, cur_m, cur_p, pidx_m, pidx_p);
    node_aggr_kernel<<<(NM + NP) / 4, 256, 0, stream>>>(
        x_mol, ea_mol, start_m, pidx_m,
        x_prot, ea_prot, start_p, pidx_p, h0_mol, h0_prot);

    mlp_qkv_kernel<<<(NM + NP) / 32, 256, 0, stream>>>(
        h0_mol, h0_prot,
        mol_w1, mol_b1, mol_w2, mol_b2, prot_w1, prot_b1, prot_w2, prot_b2,
        mp_wq, mp_bq, pm_wk, pm_bk, pm_wv, pm_bv,
        pm_wq, pm_bq, mp_wk, mp_bk, mp_wv, mp_bv,
        h_mol, h_prot, Qm, Km, Vtm, Qp, Kp, Vtp, norms);

    // both directions, 32 queries/wave: 1024 blocks x 4 waves = 4096 tasks
    attn_kernel<<<1024, 256, 0, stream>>>(Qm, Km, Vtm, Qp, Kp, Vtp, norms, partial);

    float* out = (float*)d_out;
    merge_ln_kernel<<<(NM + NP) / 4, 256, 0, stream>>>(
        partial, h_mol, h_prot, ln_mol_g, ln_mol_b, ln_prot_g, ln_prot_b, out);
}

// Round 12
// 290.304 us; speedup vs baseline: 2.1714x; 1.0131x over previous
//
#include <hip/hip_runtime.h>

#define NM 2048
#define EM 32768
#define NP 8192
#define EP 262144

typedef __attribute__((ext_vector_type(8))) short short8;
typedef __attribute__((ext_vector_type(4))) short short4v;
typedef __attribute__((ext_vector_type(4))) float f32x4;
typedef __attribute__((ext_vector_type(16))) float f32x16;

#define LOG2E 1.44269504088896340736f

__device__ __forceinline__ float e2(float x) { return __builtin_amdgcn_exp2f(x); }
__device__ __forceinline__ unsigned int pk_bf16_tr(float a, float b) {
    return __builtin_amdgcn_perm(__float_as_uint(a), __float_as_uint(b), 0x03020706u);
}
__device__ __forceinline__ unsigned short cvt_bf16(float f) {
    unsigned int u = __float_as_uint(f);
    u = (u + 0x7fff + ((u >> 16) & 1)) >> 16;   // RNE
    return (unsigned short)u;
}

// ---------------- phase 1: histogram of dst (both graphs) ----------------
__global__ __launch_bounds__(256) void hist_kernel(
    const int* __restrict__ ei_m, const int* __restrict__ ei_p,
    int* __restrict__ cnt_m, int* __restrict__ cnt_p)
{
    int idx = blockIdx.x * 256 + threadIdx.x;
    if (idx < EM) atomicAdd(&cnt_m[ei_m[EM + idx]], 1);
    int j = idx - EM;
    if (j >= 0 && j < EP) atomicAdd(&cnt_p[ei_p[EP + j]], 1);
}

// ---------------- phase 2: exclusive prefix sum (block 0 = mol, block 1 = prot) ----------------
__global__ __launch_bounds__(256) void scan_kernel(
    const int* __restrict__ cnt_m, const int* __restrict__ cnt_p,
    int* __restrict__ start_m, int* __restrict__ start_p,
    int* __restrict__ cur_m, int* __restrict__ cur_p)
{
    const int* cnt; int* start; int* cur; int n;
    if (blockIdx.x == 0) { cnt = cnt_m; start = start_m; cur = cur_m; n = NM; }
    else                 { cnt = cnt_p; start = start_p; cur = cur_p; n = NP; }
    int per = n >> 8;
    int tid = threadIdx.x;
    int base = tid * per;
    int s = 0;
    for (int i = 0; i < per; i++) s += cnt[base + i];
    __shared__ int wsum[4];
    int lane = tid & 63, w = tid >> 6;
    int v = s;
    #pragma unroll
    for (int off = 1; off < 64; off <<= 1) {
        int u = __shfl_up(v, off, 64);
        if (lane >= off) v += u;
    }
    if (lane == 63) wsum[w] = v;
    __syncthreads();
    int wo = 0;
    for (int i = 0; i < w; i++) wo += wsum[i];
    int run = wo + v - s;
    for (int i = 0; i < per; i++) {
        start[base + i] = run; cur[base + i] = run;
        run += cnt[base + i];
    }
    if (tid == 255) start[n] = run;
}

// ------- phase 3: scatter packed (edge<<sh)|src into dst-sorted order -------
__global__ __launch_bounds__(256) void scatter_kernel(
    const int* __restrict__ ei_m, const int* __restrict__ ei_p,
    int* __restrict__ cur_m, int* __restrict__ cur_p,
    int* __restrict__ pidx_m, int* __restrict__ pidx_p)
{
    int idx = blockIdx.x * 256 + threadIdx.x;
    if (idx < EM) {
        int d = ei_m[EM + idx];
        int pos = atomicAdd(&cur_m[d], 1);
        pidx_m[pos] = (idx << 11) | ei_m[idx];          // NM=2048 -> 11 src bits
    }
    int j = idx - EM;
    if (j >= 0 && j < EP) {
        int d = ei_p[EP + j];
        int pos = atomicAdd(&cur_p[d], 1);
        pidx_p[pos] = (j << 13) | ei_p[j];              // NP=8192 -> 13 src bits
    }
}

// ------- phase 4: segmented reduce; h0 = x + mean(relu(x[src]+ea)) -> bf16 -------
__global__ __launch_bounds__(256) void node_aggr_kernel(
    const float* __restrict__ x_m, const float* __restrict__ ea_m,
    const int* __restrict__ start_m, const int* __restrict__ pidx_m,
    const float* __restrict__ x_p, const float* __restrict__ ea_p,
    const int* __restrict__ start_p, const int* __restrict__ pidx_p,
    unsigned short* __restrict__ h0b_m, unsigned short* __restrict__ h0b_p)
{
    int wave = threadIdx.x >> 6, lane = threadIdx.x & 63;
    int nid = blockIdx.x * 4 + wave;
    const float *x, *ea; const int *start, *pidx; unsigned short* h0b; int n, sh, msk;
    if (nid < NM) { x = x_m; ea = ea_m; start = start_m; pidx = pidx_m; h0b = h0b_m; n = nid; sh = 11; msk = 2047; }
    else          { x = x_p; ea = ea_p; start = start_p; pidx = pidx_p; h0b = h0b_p; n = nid - NM; sh = 13; msk = 8191; }
    int b  = __builtin_amdgcn_readfirstlane(start[n]);
    int e  = __builtin_amdgcn_readfirstlane(start[n + 1]);
    int deg = e - b;
    const int* pp = pidx + b;
    float acc = 0.f;
    int j = 0;
    for (; j + 8 <= deg; j += 8) {
        int v0 = __builtin_amdgcn_readfirstlane(pp[j]);
        int v1 = __builtin_amdgcn_readfirstlane(pp[j + 1]);
        int v2 = __builtin_amdgcn_readfirstlane(pp[j + 2]);
        int v3 = __builtin_amdgcn_readfirstlane(pp[j + 3]);
        int v4 = __builtin_amdgcn_readfirstlane(pp[j + 4]);
        int v5 = __builtin_amdgcn_readfirstlane(pp[j + 5]);
        int v6 = __builtin_amdgcn_readfirstlane(pp[j + 6]);
        int v7 = __builtin_amdgcn_readfirstlane(pp[j + 7]);
        float a0 = ea[(size_t)(((unsigned)v0) >> sh) * 64 + lane];
        float a1 = ea[(size_t)(((unsigned)v1) >> sh) * 64 + lane];
        float a2 = ea[(size_t)(((unsigned)v2) >> sh) * 64 + lane];
        float a3 = ea[(size_t)(((unsigned)v3) >> sh) * 64 + lane];
        float a4 = ea[(size_t)(((unsigned)v4) >> sh) * 64 + lane];
        float a5 = ea[(size_t)(((unsigned)v5) >> sh) * 64 + lane];
        float a6 = ea[(size_t)(((unsigned)v6) >> sh) * 64 + lane];
        float a7 = ea[(size_t)(((unsigned)v7) >> sh) * 64 + lane];
        float y0 = x[(size_t)(v0 & msk) * 64 + lane];
        float y1 = x[(size_t)(v1 & msk) * 64 + lane];
        float y2 = x[(size_t)(v2 & msk) * 64 + lane];
        float y3 = x[(size_t)(v3 & msk) * 64 + lane];
        float y4 = x[(size_t)(v4 & msk) * 64 + lane];
        float y5 = x[(size_t)(v5 & msk) * 64 + lane];
        float y6 = x[(size_t)(v6 & msk) * 64 + lane];
        float y7 = x[(size_t)(v7 & msk) * 64 + lane];
        acc += fmaxf(y0 + a0, 0.f); acc += fmaxf(y1 + a1, 0.f);
        acc += fmaxf(y2 + a2, 0.f); acc += fmaxf(y3 + a3, 0.f);
        acc += fmaxf(y4 + a4, 0.f); acc += fmaxf(y5 + a5, 0.f);
        acc += fmaxf(y6 + a6, 0.f); acc += fmaxf(y7 + a7, 0.f);
    }
    for (; j < deg; ++j) {
        int v0 = __builtin_amdgcn_readfirstlane(pp[j]);
        acc += fmaxf(x[(size_t)(v0 & msk) * 64 + lane] + ea[(size_t)(((unsigned)v0) >> sh) * 64 + lane], 0.f);
    }
    float aggr = acc / fmaxf((float)deg, 1.f);
    h0b[(size_t)n * 64 + lane] = cvt_bf16(x[(size_t)n * 64 + lane] + aggr);
}

// ------- weight prep: 10 matrices fp32 [in][out] -> bf16 TRANSPOSED Wt[out][in] -------
// order: 0=W1,1=W2,2=Wq,3=Wk,4=Wv (mol), 5..9 same (prot)
__global__ __launch_bounds__(256) void prep_w_kernel(
    const float* __restrict__ w0, const float* __restrict__ w1, const float* __restrict__ w2,
    const float* __restrict__ w3, const float* __restrict__ w4, const float* __restrict__ w5,
    const float* __restrict__ w6, const float* __restrict__ w7, const float* __restrict__ w8,
    const float* __restrict__ w9, unsigned short* __restrict__ wt)
{
    int b = blockIdx.x;
    int t = b >> 4;                       // matrix 0..9 (16 blocks each)
    int e = (b & 15) * 256 + threadIdx.x; // element 0..4095
    const float* src;
    switch (t) {
        case 0: src = w0; break; case 1: src = w1; break; case 2: src = w2; break;
        case 3: src = w3; break; case 4: src = w4; break; case 5: src = w5; break;
        case 6: src = w6; break; case 7: src = w7; break; case 8: src = w8; break;
        default: src = w9; break;
    }
    int n = e >> 6, k = e & 63;
    wt[t * 4096 + e] = cvt_bf16(src[k * 64 + n]);   // wt[t][n*64+k] = W[k][n]
}

// ------- MFMA MLP+QKV: one wave per 16-row tile, zero barriers -------
// GEMM chain: h1=relu(h0@W1+b1) -> h=relu(h1@W2+b2) (fp32 out) -> Q,K,V (bf16).
// A-frag: 16B from bf16 rows; B-frag: 16B from transposed Wt. C-layout: col=lane&15,
// row=quad*4+reg (guide-verified). Row->A transform via per-wave LDS bf16 tile.
__global__ __launch_bounds__(256) void mlp_qkv_kernel(
    const unsigned short* __restrict__ h0b_m, const unsigned short* __restrict__ h0b_p,
    const unsigned short* __restrict__ wt,
    const float* __restrict__ b1m_, const float* __restrict__ b2m_,
    const float* __restrict__ bqm_, const float* __restrict__ bkm_, const float* __restrict__ bvm_,
    const float* __restrict__ b1p_, const float* __restrict__ b2p_,
    const float* __restrict__ bqp_, const float* __restrict__ bkp_, const float* __restrict__ bvp_,
    float* __restrict__ hm, float* __restrict__ hp,
    unsigned short* __restrict__ Qm, unsigned short* __restrict__ Km, unsigned short* __restrict__ Vtm,
    unsigned short* __restrict__ Qp, unsigned short* __restrict__ Kp, unsigned short* __restrict__ Vtp,
    int* __restrict__ norms)
{
    __shared__ unsigned short tile[4][2][16][72];   // [wave][buf][row][ch+pad], 144B rows (16B-aligned)
    int t = threadIdx.x, wave = t >> 6, lane = t & 63;
    int col = lane & 15, quad = lane >> 4;
    int blk = blockIdx.x;
    const unsigned short* h0b; const float *b1, *b2, *bq, *bk, *bv;
    float* hout; unsigned short *Q, *K, *Vt; int N, row0, wofs, nb;
    if (blk < NM / 64) {
        h0b = h0b_m; b1 = b1m_; b2 = b2m_; bq = bqm_; bk = bkm_; bv = bvm_;
        hout = hm; Q = Qm; K = Km; Vt = Vtm; N = NM;
        row0 = blk * 64 + wave * 16; wofs = 0; nb = 0;
    } else {
        h0b = h0b_p; b1 = b1p_; b2 = b2p_; bq = bqp_; bk = bkp_; bv = bvp_;
        hout = hp; Q = Qp; K = Kp; Vt = Vtp; N = NP;
        row0 = (blk - NM / 64) * 64 + wave * 16; wofs = 5 * 4096; nb = 2;
    }
    const f32x4 zero4 = {0.f, 0.f, 0.f, 0.f};
    // per-lane B-frag base: Wt row (ntile*16+col), k-offset quad*8
    const unsigned short* wb = wt + wofs + (size_t)col * 64 + quad * 8;

    // A0 from h0 bf16 rows
    const unsigned short* ar = h0b + (size_t)(row0 + col) * 64 + quad * 8;
    short8 aL = *(const short8*)ar;
    short8 aH = *(const short8*)(ar + 32);

    // ---- GEMM1: hidden = relu(h0@W1+b1) -> LDS buf0 ----
    #pragma unroll
    for (int nt = 0; nt < 4; ++nt) {
        short8 bL = *(const short8*)(wb + nt * 1024);
        short8 bH = *(const short8*)(wb + nt * 1024 + 32);
        f32x4 d = __builtin_amdgcn_mfma_f32_16x16x32_bf16(aL, bL, zero4, 0, 0, 0);
        d = __builtin_amdgcn_mfma_f32_16x16x32_bf16(aH, bH, d, 0, 0, 0);
        float bias = b1[nt * 16 + col];
        #pragma unroll
        for (int r = 0; r < 4; ++r)
            tile[wave][0][quad * 4 + r][nt * 16 + col] = cvt_bf16(fmaxf(d[r] + bias, 0.f));
    }
    short8 a1L = *(const short8*)&tile[wave][0][col][quad * 8];
    short8 a1H = *(const short8*)&tile[wave][0][col][32 + quad * 8];

    // ---- GEMM2: h = relu(hidden@W2+b2) -> global fp32 + LDS buf1 ----
    #pragma unroll
    for (int nt = 0; nt < 4; ++nt) {
        short8 bL = *(const short8*)(wb + 4096 + nt * 1024);
        short8 bH = *(const short8*)(wb + 4096 + nt * 1024 + 32);
        f32x4 d = __builtin_amdgcn_mfma_f32_16x16x32_bf16(a1L, bL, zero4, 0, 0, 0);
        d = __builtin_amdgcn_mfma_f32_16x16x32_bf16(a1H, bH, d, 0, 0, 0);
        float bias = b2[nt * 16 + col];
        #pragma unroll
        for (int r = 0; r < 4; ++r) {
            float v = fmaxf(d[r] + bias, 0.f);
            hout[(size_t)(row0 + quad * 4 + r) * 64 + nt * 16 + col] = v;
            tile[wave][1][quad * 4 + r][nt * 16 + col] = cvt_bf16(v);
        }
    }
    short8 a2L = *(const short8*)&tile[wave][1][col][quad * 8];
    short8 a2H = *(const short8*)&tile[wave][1][col][32 + quad * 8];

    // ---- GEMM3: Q (scaled into exp2 domain) + row-norm ----
    float q2[4] = {0.f, 0.f, 0.f, 0.f};
    #pragma unroll
    for (int nt = 0; nt < 4; ++nt) {
        short8 bL = *(const short8*)(wb + 2 * 4096 + nt * 1024);
        short8 bH = *(const short8*)(wb + 2 * 4096 + nt * 1024 + 32);
        f32x4 d = __builtin_amdgcn_mfma_f32_16x16x32_bf16(a2L, bL, zero4, 0, 0, 0);
        d = __builtin_amdgcn_mfma_f32_16x16x32_bf16(a2H, bH, d, 0, 0, 0);
        float bias = bq[nt * 16 + col];
        #pragma unroll
        for (int r = 0; r < 4; ++r) {
            float qv = (d[r] + bias) * (0.25f * LOG2E);
            Q[(size_t)(row0 + quad * 4 + r) * 64 + nt * 16 + col] = cvt_bf16(qv);
            q2[r] += qv * qv;
        }
    }
    float qmx = 0.f;
    #pragma unroll
    for (int r = 0; r < 4; ++r) {
        float s = q2[r];
        s += __shfl_xor(s, 1, 64); s += __shfl_xor(s, 2, 64);
        s += __shfl_xor(s, 4, 64); s += __shfl_xor(s, 8, 64);
        qmx = fmaxf(qmx, s);   // full-row sumsq >= any head sumsq -> valid C-S bound
    }

    // ---- GEMM4: K + row-norm ----
    float k2[4] = {0.f, 0.f, 0.f, 0.f};
    #pragma unroll
    for (int nt = 0; nt < 4; ++nt) {
        short8 bL = *(const short8*)(wb + 3 * 4096 + nt * 1024);
        short8 bH = *(const short8*)(wb + 3 * 4096 + nt * 1024 + 32);
        f32x4 d = __builtin_amdgcn_mfma_f32_16x16x32_bf16(a2L, bL, zero4, 0, 0, 0);
        d = __builtin_amdgcn_mfma_f32_16x16x32_bf16(a2H, bH, d, 0, 0, 0);
        float bias = bk[nt * 16 + col];
        #pragma unroll
        for (int r = 0; r < 4; ++r) {
            float kv = d[r] + bias;
            K[(size_t)(row0 + quad * 4 + r) * 64 + nt * 16 + col] = cvt_bf16(kv);
            k2[r] += kv * kv;
        }
    }
    float kmx = 0.f;
    #pragma unroll
    for (int r = 0; r < 4; ++r) {
        float s = k2[r];
        s += __shfl_xor(s, 1, 64); s += __shfl_xor(s, 2, 64);
        s += __shfl_xor(s, 4, 64); s += __shfl_xor(s, 8, 64);
        kmx = fmaxf(kmx, s);
    }

    // ---- GEMM5: V (transposed store: 4 consecutive rows/lane = one 8B store) ----
    #pragma unroll
    for (int nt = 0; nt < 4; ++nt) {
        short8 bL = *(const short8*)(wb + 4 * 4096 + nt * 1024);
        short8 bH = *(const short8*)(wb + 4 * 4096 + nt * 1024 + 32);
        f32x4 d = __builtin_amdgcn_mfma_f32_16x16x32_bf16(a2L, bL, zero4, 0, 0, 0);
        d = __builtin_amdgcn_mfma_f32_16x16x32_bf16(a2H, bH, d, 0, 0, 0);
        float bias = bv[nt * 16 + col];
        short4v vv;
        vv.x = (short)cvt_bf16(d[0] + bias);
        vv.y = (short)cvt_bf16(d[1] + bias);
        vv.z = (short)cvt_bf16(d[2] + bias);
        vv.w = (short)cvt_bf16(d[3] + bias);
        *(short4v*)(Vt + (size_t)(nt * 16 + col) * N + row0 + quad * 4) = vv;
    }

    // wave-level norm max + atomics
    qmx = fmaxf(qmx, __shfl_xor(qmx, 16, 64)); qmx = fmaxf(qmx, __shfl_xor(qmx, 32, 64));
    kmx = fmaxf(kmx, __shfl_xor(kmx, 16, 64)); kmx = fmaxf(kmx, __shfl_xor(kmx, 32, 64));
    if (lane == 0) {
        atomicMax(&norms[nb],     __float_as_int(sqrtf(qmx)));
        atomicMax(&norms[nb + 1], __float_as_int(sqrtf(kmx)));
    }
}

// ------- MFMA flash-attention: 32x32x16 QK, fixed C-S bound m, deferred-PV pipeline -------
__global__ __launch_bounds__(256) void attn_kernel(
    const unsigned short* __restrict__ Qm, const unsigned short* __restrict__ Km,
    const unsigned short* __restrict__ Vtm,
    const unsigned short* __restrict__ Qp, const unsigned short* __restrict__ Kp,
    const unsigned short* __restrict__ Vtp,
    const int* __restrict__ norms, float* __restrict__ partial)
{
    __shared__ unsigned int plds[4][2][2][16][20];   // [wave][qtile][buf][qrow][16+pad]
    int t = threadIdx.x;
    int wave = t >> 6;
    int lane = t & 63;
    int qrow = lane & 15;
    int quad = lane >> 4;
    int q5   = lane & 31;
    int half = lane >> 5;
    int qtl  = q5 >> 4;
    int dwb  = half * 2;
    int W = blockIdx.x * 4 + wave;

    const unsigned short *Q, *K, *Vt; int Nk; float m;
    int chunk, h, qt2, Tbase, T1off;
    if (W < 2048) {
        Q = Qm; K = Kp; Vt = Vtp; Nk = NP;
        m = __int_as_float(norms[0]) * __int_as_float(norms[3]);
        chunk = W & 7; h = (W >> 3) & 3; qt2 = W >> 5;
        Tbase = W + qt2 * 32; T1off = 32;
    } else {
        int W2 = W - 2048;
        Q = Qp; K = Km; Vt = Vtm; Nk = NM;
        m = __int_as_float(norms[2]) * __int_as_float(norms[1]);
        chunk = W2 & 1; h = (W2 >> 1) & 3; qt2 = W2 >> 3;
        Tbase = 4096 + W2 + qt2 * 8; T1off = 8;
    }

    short8 qf = *(const short8*)(Q + ((size_t)(qt2 * 32 + q5)) * 64 + h * 16 + half * 8);

    const f32x16 zero16 = {0.f,0.f,0.f,0.f,0.f,0.f,0.f,0.f,0.f,0.f,0.f,0.f,0.f,0.f,0.f,0.f};
    const f32x4 zero4 = {0.f, 0.f, 0.f, 0.f};
    int kbase = chunk * 1024;
    const unsigned short* krow = K + (size_t)(kbase + q5) * 64 + h * 16 + half * 8;
    const unsigned short* vrow = Vt + ((size_t)(h * 16 + qrow)) * Nk + kbase + quad * 8;

    float l = 0.0f;
    f32x4 accA = zero4, accB = zero4;

    short8 kf_0, kf_1, vf_0, vf_1;
    kf_0 = *(const short8*)(krow);
    kf_1 = *(const short8*)(krow + 32 * 64);
    vf_0 = *(const short8*)(vrow);
    vf_1 = *(const short8*)(vrow + 32);

    short8 vf_prev;

#define QK_PHASE(IT, SLOT, BUF)                                                             \
    {                                                                                       \
        short8 kf = kf_##SLOT; short8 vf = vf_##SLOT;                                       \
        if ((IT) < 30) {                                                                    \
            int off = ((IT) + 2) * 32;                                                      \
            kf_##SLOT = *(const short8*)(krow + (size_t)off * 64);                          \
            vf_##SLOT = *(const short8*)(vrow + off);                                       \
        }                                                                                   \
        f32x16 s = __builtin_amdgcn_mfma_f32_32x32x16_bf16(kf, qf, zero16, 0, 0, 0);        \
        float p0  = e2(s[0] - m),  p1  = e2(s[1] - m),  p2  = e2(s[2] - m),  p3  = e2(s[3] - m);  \
        float p4  = e2(s[4] - m),  p5  = e2(s[5] - m),  p6  = e2(s[6] - m),  p7  = e2(s[7] - m);  \
        float p8  = e2(s[8] - m),  p9  = e2(s[9] - m),  p10 = e2(s[10] - m), p11 = e2(s[11] - m); \
        float p12 = e2(s[12] - m), p13 = e2(s[13] - m), p14 = e2(s[14] - m), p15 = e2(s[15] - m); \
        l += (((p0 + p1) + (p2 + p3)) + ((p4 + p5) + (p6 + p7)))                            \
           + (((p8 + p9) + (p10 + p11)) + ((p12 + p13) + (p14 + p15)));                     \
        uint2 w0; w0.x = pk_bf16_tr(p0, p1);   w0.y = pk_bf16_tr(p2, p3);                   \
        uint2 w1; w1.x = pk_bf16_tr(p4, p5);   w1.y = pk_bf16_tr(p6, p7);                   \
        uint2 w2; w2.x = pk_bf16_tr(p8, p9);   w2.y = pk_bf16_tr(p10, p11);                 \
        uint2 w3; w3.x = pk_bf16_tr(p12, p13); w3.y = pk_bf16_tr(p14, p15);                 \
        *(uint2*)&plds[wave][qtl][BUF][qrow][dwb]      = w0;                                \
        *(uint2*)&plds[wave][qtl][BUF][qrow][dwb + 4]  = w1;                                \
        *(uint2*)&plds[wave][qtl][BUF][qrow][dwb + 8]  = w2;                                \
        *(uint2*)&plds[wave][qtl][BUF][qrow][dwb + 12] = w3;                                \
        vf_cur = vf;                                                                        \
    }

#define STEP(IT, SLOT, BUF, PREV)                                                           \
    {                                                                                       \
        short8 pfA = *(short8*)&plds[wave][0][PREV][qrow][quad * 4];                        \
        short8 pfB = *(short8*)&plds[wave][1][PREV][qrow][quad * 4];                        \
        short8 vf_cur;                                                                      \
        QK_PHASE(IT, SLOT, BUF)                                                             \
        accA = __builtin_amdgcn_mfma_f32_16x16x32_bf16(vf_prev, pfA, accA, 0, 0, 0);        \
        accB = __builtin_amdgcn_mfma_f32_16x16x32_bf16(vf_prev, pfB, accB, 0, 0, 0);        \
        vf_prev = vf_cur;                                                                   \
    }

    {
        short8 vf_cur;
        QK_PHASE(0, 0, 0)
        vf_prev = vf_cur;
    }
    for (int p = 0; p < 15; ++p) {
        STEP(2 * p + 1, 1, 1, 0)
        STEP(2 * p + 2, 0, 0, 1)
    }
    STEP(31, 1, 1, 0)
    {
        short8 pfA = *(short8*)&plds[wave][0][1][qrow][quad * 4];
        short8 pfB = *(short8*)&plds[wave][1][1][qrow][quad * 4];
        accA = __builtin_amdgcn_mfma_f32_16x16x32_bf16(vf_prev, pfA, accA, 0, 0, 0);
        accB = __builtin_amdgcn_mfma_f32_16x16x32_bf16(vf_prev, pfB, accB, 0, 0, 0);
    }
#undef STEP
#undef QK_PHASE

    float ltot = l + __shfl_xor(l, 32, 64);

    float* pb0 = partial + (size_t)Tbase * 288;
    *(f32x4*)&pb0[qrow * 16 + quad * 4] = accA;
    float* pb1 = partial + (size_t)(Tbase + T1off) * 288;
    *(f32x4*)&pb1[qrow * 16 + quad * 4] = accB;
    if (lane < 16)       pb0[272 + q5] = ltot;
    else if (lane < 32)  pb1[272 + (q5 - 16)] = ltot;
}

// ------- merge chunk partials + residual + layernorm (uniform m: plain sums) -------
__global__ __launch_bounds__(256) void merge_ln_kernel(
    const float* __restrict__ partial,
    const float* __restrict__ h_m, const float* __restrict__ h_p,
    const float* __restrict__ gm, const float* __restrict__ bm,
    const float* __restrict__ gp, const float* __restrict__ bp_,
    float* __restrict__ out)
{
    int t = threadIdx.x;
    int grow = blockIdx.x * 4 + (t >> 6);
    int c = t & 63;
    const float *pbase, *hbuf, *g, *bb; float* o; int NC, row;
    if (grow < NM) { pbase = partial;               hbuf = h_m; g = gm; bb = bm;  o = out;             NC = 8; row = grow; }
    else           { pbase = partial + 4096 * 288;  hbuf = h_p; g = gp; bb = bp_; o = out + NM * 64;   NC = 2; row = grow - NM; }
    int hi = c >> 4, d = c & 15;
    int qt = row >> 4, ql = row & 15;
    const float* base = pbase + (size_t)(qt * 4 + hi) * NC * 288;
    float L = 0.0f, A = 0.0f;
    for (int cc = 0; cc < NC; ++cc) {
        L += base[cc * 288 + 272 + ql];
        A += base[cc * 288 + ql * 16 + d];
    }
    float v = hbuf[(size_t)row * 64 + c] + A / L;
    float s = v;
    #pragma unroll
    for (int o2 = 32; o2 >= 1; o2 >>= 1) s += __shfl_xor(s, o2, 64);
    float mu = s * (1.0f / 64.0f);
    float dv = v - mu;
    float sq = dv * dv;
    #pragma unroll
    for (int o2 = 32; o2 >= 1; o2 >>= 1) sq += __shfl_xor(sq, o2, 64);
    float var = sq * (1.0f / 64.0f);
    o[(size_t)row * 64 + c] = dv * rsqrtf(var + 1e-5f) * g[c] + bb[c];
}

extern "C" void kernel_launch(void* const* d_in, const int* in_sizes, int n_in,
                              void* d_out, int out_size, void* d_ws, size_t ws_size,
                              hipStream_t stream)
{
    const float* x_mol   = (const float*)d_in[0];
    const int*   ei_mol  = (const int*)  d_in[1];
    const float* ea_mol  = (const float*)d_in[2];
    const float* x_prot  = (const float*)d_in[3];
    const int*   ei_prot = (const int*)  d_in[4];
    const float* ea_prot = (const float*)d_in[5];
    const float* mol_w1  = (const float*)d_in[6];
    const float* mol_b1  = (const float*)d_in[7];
    const float* mol_w2  = (const float*)d_in[8];
    const float* mol_b2  = (const float*)d_in[9];
    const float* prot_w1 = (const float*)d_in[10];
    const float* prot_b1 = (const float*)d_in[11];
    const float* prot_w2 = (const float*)d_in[12];
    const float* prot_b2 = (const float*)d_in[13];
    const float* mp_wq = (const float*)d_in[14]; const float* mp_bq = (const float*)d_in[15];
    const float* mp_wk = (const float*)d_in[16]; const float* mp_bk = (const float*)d_in[17];
    const float* mp_wv = (const float*)d_in[18]; const float* mp_bv = (const float*)d_in[19];
    const float* pm_wq = (const float*)d_in[20]; const float* pm_bq = (const float*)d_in[21];
    const float* pm_wk = (const float*)d_in[22]; const float* pm_bk = (const float*)d_in[23];
    const float* pm_wv = (const float*)d_in[24]; const float* pm_bv = (const float*)d_in[25];
    const float* ln_mol_g  = (const float*)d_in[26];
    const float* ln_mol_b  = (const float*)d_in[27];
    const float* ln_prot_g = (const float*)d_in[28];
    const float* ln_prot_b = (const float*)d_in[29];

    float* ws = (float*)d_ws;
    // float region
    float* h_mol   = ws;                         // 131072
    float* h_prot  = h_mol + 131072;             // 524288
    float* partial = h_prot + 524288;            // 8192*288 (mol tasks 0..4095, prot 4096..8191)
    // h0 bf16 aliases partial (dead before attn writes partial)
    unsigned short* h0b_mol  = (unsigned short*)partial;      // 131072 shorts
    unsigned short* h0b_prot = h0b_mol + 131072;              // 524288 shorts
    // int region
    int* ip      = (int*)(partial + 2359296);
    int* cnt_m   = ip;                 // 2048
    int* cnt_p   = cnt_m + 2048;       // 8192
    int* norms   = cnt_p + 8192;       // 4  (0=Qm,1=Km,2=Qp,3=Kp; float bits)
    int* start_m = norms + 4;          // 2052 (2049 used)
    int* start_p = start_m + 2052;     // 8196 (8193 used)
    int* cur_m   = start_p + 8196;     // 2048
    int* cur_p   = cur_m + 2048;       // 8192
    int* pidx_m  = cur_p + 8192;       // 32768
    int* pidx_p  = pidx_m + 32768;     // 262144
    // bf16 region
    unsigned short* bf = (unsigned short*)(pidx_p + 262144);
    unsigned short* Qm  = bf;            // 131072
    unsigned short* Km  = Qm + 131072;   // 131072
    unsigned short* Vtm = Km + 131072;   // 131072  [64][NM]
    unsigned short* Qp  = Vtm + 131072;  // 524288
    unsigned short* Kp  = Qp + 524288;   // 524288
    unsigned short* Vtp = Kp + 524288;   // 524288  [64][NP]
    unsigned short* wt  = Vtp + 524288;  // 40960 (10 x 64x64 bf16 transposed weights)

    hipMemsetAsync(cnt_m, 0, (size_t)(2048 + 8192 + 4) * sizeof(int), stream);

    // transposed bf16 weights (mol: W1,W2,Wq,Wk,Wv then prot)
    prep_w_kernel<<<160, 256, 0, stream>>>(
        mol_w1, mol_w2, mp_wq, pm_wk, pm_wv,
        prot_w1, prot_w2, pm_wq, mp_wk, mp_wv, wt);

    const int EB = (EM + EP) / 256;   // 1152
    hist_kernel<<<EB, 256, 0, stream>>>(ei_mol, ei_prot, cnt_m, cnt_p);
    scan_kernel<<<2, 256, 0, stream>>>(cnt_m, cnt_p, start_m, start_p, cur_m, cur_p);
    scatter_kernel<<<EB, 256, 0, stream>>>(ei_mol, ei_prot, cur_m, cur_p, pidx_m, pidx_p);
    node_aggr_kernel<<<(NM + NP) / 4, 256, 0, stream>>>(
        x_mol, ea_mol, start_m, pidx_m,
        x_prot, ea_prot, start_p, pidx_p, h0b_mol, h0b_prot);

    mlp_qkv_kernel<<<(NM + NP) / 64, 256, 0, stream>>>(
        h0b_mol, h0b_prot, wt,
        mol_b1, mol_b2, mp_bq, pm_bk, pm_bv,
        prot_b1, prot_b2, pm_bq, mp_bk, mp_bv,
        h_mol, h_prot, Qm, Km, Vtm, Qp, Kp, Vtp, norms);

    // both directions, 32 queries/wave: 1024 blocks x 4 waves = 4096 tasks
    attn_kernel<<<1024, 256, 0, stream>>>(Qm, Km, Vtm, Qp, Kp, Vtp, norms, partial);

    float* out = (float*)d_out;
    merge_ln_kernel<<<(NM + NP) / 4, 256, 0, stream>>>(
        partial, h_mol, h_prot, ln_mol_g, ln_mol_b, ln_prot_g, ln_prot_b, out);
}